// Round 1
// baseline (2037.001 us; speedup 1.0000x reference)
//
#include <hip/hip_runtime.h>
#include <hip/hip_bf16.h>
#include <cmath>

#define NL      6
#define NHEADS  4
#define DIM     128
#define FFD     512
#define CMID_   8
#define COUT_   16
#define QOUT_   10
#define MAXLEN_ 512
#define NCLS_   3
#define BB      32
#define TT      500
#define FIN_    232
#define MM      (BB*TT)
#define HD      32
#define NKT     8
#define RELLEN  (2*MAXLEN_-1)

// ---------------- encoder precompute (1 block) ----------------
// alpha[q] = sum_c proj_w[c]*queries[q,c]
// E[q,d]   = sum_o gamma[o]*embed_w[o*QOUT+q, d],  gamma[o]=sum_c pw[c]*fc_w[c,o]
// c0[d]    = sum_{o,q} delta[o]*embed_w[o*QOUT+q, d] + embed_b[d]
//            delta[o] = sum_c (proj_b[c]+pe[c])*fc_w[c,o] + fc_b[o]
__global__ __launch_bounds__(128) void enc_pre_kernel(
    const float* __restrict__ proj_w, const float* __restrict__ proj_b,
    const float* __restrict__ queries, const float* __restrict__ fc_w,
    const float* __restrict__ fc_b, const float* __restrict__ embed_w,
    const float* __restrict__ embed_b,
    float* __restrict__ alpha, float* __restrict__ E, float* __restrict__ c0)
{
    __shared__ float pw[CMID_], cb[CMID_], gam[COUT_], del[COUT_];
    int t = threadIdx.x;
    if (t < CMID_) { pw[t] = proj_w[t]; cb[t] = proj_b[t] + ((t & 1) ? 1.f : 0.f); }
    __syncthreads();
    if (t < QOUT_) {
        float a = 0.f;
        for (int c = 0; c < CMID_; ++c) a += pw[c] * queries[t*CMID_ + c];
        alpha[t] = a;
    }
    if (t < COUT_) {
        float gg = 0.f, dd = 0.f;
        for (int c = 0; c < CMID_; ++c) {
            gg += pw[c] * fc_w[c*COUT_ + t];
            dd += cb[c] * fc_w[c*COUT_ + t];
        }
        gam[t] = gg; del[t] = dd + fc_b[t];
    }
    __syncthreads();
    for (int i = t; i < QOUT_*DIM; i += 128) {
        int q = i / DIM, d = i % DIM;
        float e = 0.f;
        for (int o = 0; o < COUT_; ++o) e += gam[o] * embed_w[(o*QOUT_ + q)*DIM + d];
        E[i] = e;
    }
    {
        float c = embed_b[t];
        for (int o = 0; o < COUT_; ++o) {
            float dl = del[o];
            for (int q = 0; q < QOUT_; ++q) c += dl * embed_w[(o*QOUT_ + q)*DIM + t];
        }
        c0[t] = c;
    }
}

// ---------------- encoder main: h[b,t,:] = sum_q m_q * E[q,:] + c0 ----------------
__global__ __launch_bounds__(64) void enc_kernel(
    const float* __restrict__ x1, const float* __restrict__ alpha,
    const float* __restrict__ E, const float* __restrict__ c0,
    float* __restrict__ h)
{
    int bt = blockIdx.x;
    int lane = threadIdx.x;
    const float* xr = x1 + (size_t)bt * FIN_;
    float xv[4];
    bool vld[4];
    #pragma unroll
    for (int i = 0; i < 4; ++i) {
        int f = lane + (i << 6);
        vld[i] = (f < FIN_);
        xv[i] = vld[i] ? xr[f] : 0.f;
    }
    float vmax = -INFINITY, vmin = INFINITY;
    #pragma unroll
    for (int i = 0; i < 4; ++i) if (vld[i]) { vmax = fmaxf(vmax, xv[i]); vmin = fminf(vmin, xv[i]); }
    #pragma unroll
    for (int off = 1; off < 64; off <<= 1) {
        vmax = fmaxf(vmax, __shfl_xor(vmax, off));
        vmin = fminf(vmin, __shfl_xor(vmin, off));
    }
    float mq[QOUT_];
    for (int q = 0; q < QOUT_; ++q) {
        float a = alpha[q];
        float Mx = (a >= 0.f) ? a * vmax : a * vmin;  // max_f of a*x
        float se = 0.f, sx = 0.f;
        #pragma unroll
        for (int i = 0; i < 4; ++i) if (vld[i]) {
            float e = expf(fmaf(a, xv[i], -Mx));
            se += e; sx += e * xv[i];
        }
        #pragma unroll
        for (int off = 1; off < 64; off <<= 1) { se += __shfl_xor(se, off); sx += __shfl_xor(sx, off); }
        mq[q] = sx / se;
    }
    #pragma unroll
    for (int k = 0; k < 2; ++k) {
        int d = lane + (k << 6);
        float hv = c0[d];
        #pragma unroll
        for (int q = 0; q < QOUT_; ++q) hv = fmaf(mq[q], E[q*DIM + d], hv);
        h[(size_t)bt*DIM + d] = hv;
    }
}

// ---------------- tiled fp32 GEMM: C[M,N] = A[M,K] @ W[K,N] + bias, opt ReLU --------
// BM=BN=64, BK=16, 256 threads, 4x4 per thread.
__global__ __launch_bounds__(256) void gemm_kernel(
    const float* __restrict__ A, const float* __restrict__ W,
    const float* __restrict__ bias, float* __restrict__ C,
    int N, int K, int relu)
{
    __shared__ __align__(16) float As[16][68];  // transposed, padded: 16B-aligned rows
    __shared__ __align__(16) float Ws[16][64];
    const int tid = threadIdx.x;
    const int row0 = blockIdx.y << 6;
    const int col0 = blockIdx.x << 6;
    const int tx = tid & 15, ty = tid >> 4;
    const int ar = tid >> 2, ac = (tid & 3) << 2;
    const int wr = tid >> 4, wc = (tid & 15) << 2;
    float acc[4][4] = {};
    for (int k0 = 0; k0 < K; k0 += 16) {
        float4 av = *reinterpret_cast<const float4*>(A + (size_t)(row0 + ar)*K + k0 + ac);
        As[ac+0][ar] = av.x; As[ac+1][ar] = av.y; As[ac+2][ar] = av.z; As[ac+3][ar] = av.w;
        *reinterpret_cast<float4*>(&Ws[wr][wc]) =
            *reinterpret_cast<const float4*>(W + (size_t)(k0 + wr)*N + col0 + wc);
        __syncthreads();
        #pragma unroll
        for (int kk = 0; kk < 16; ++kk) {
            float4 a4 = *reinterpret_cast<const float4*>(&As[kk][ty << 2]);
            float4 b4 = *reinterpret_cast<const float4*>(&Ws[kk][tx << 2]);
            float a[4] = {a4.x, a4.y, a4.z, a4.w};
            float b[4] = {b4.x, b4.y, b4.z, b4.w};
            #pragma unroll
            for (int i = 0; i < 4; ++i)
                #pragma unroll
                for (int j = 0; j < 4; ++j)
                    acc[i][j] = fmaf(a[i], b[j], acc[i][j]);
        }
        __syncthreads();
    }
    #pragma unroll
    for (int i = 0; i < 4; ++i) {
        int r = row0 + (ty << 2) + i;
        #pragma unroll
        for (int j = 0; j < 4; ++j) {
            int c = col0 + (tx << 2) + j;
            float v = acc[i][j] + bias[c];
            if (relu) v = fmaxf(v, 0.f);
            C[(size_t)r*N + c] = v;
        }
    }
}

// ---------------- fused flash attention, fp32 ----------------
// grid: B*NHEADS*NKT blocks; block 256 = 64 q-rows x 4 col-lanes.
// qkv layout: [b,t, 0:128]=q, [128:256]=k, [256:384]=v
__global__ __launch_bounds__(256) void attn_kernel(
    const float* __restrict__ qkv, const float* __restrict__ rel,
    float* __restrict__ o)
{
    __shared__ __align__(16) float Ks[64][36];
    __shared__ __align__(16) float Vs[64][36];
    __shared__ float rl[RELLEN];
    const int bid = blockIdx.x;
    const int qt = bid & 7;
    const int bh = bid >> 3;
    const int hh = bh & 3;
    const int b  = bh >> 2;
    const int tid = threadIdx.x;
    for (int i = tid; i < RELLEN; i += 256) rl[i] = rel[i];
    const int q0 = qt << 6;
    const int r = tid >> 2, j = tid & 3;
    const int tq = q0 + r;
    const bool qvalid = (tq < TT);
    const float* qp = qkv + (size_t)(b*TT + (qvalid ? tq : 0))*384 + hh*HD;
    float qreg[HD];
    #pragma unroll
    for (int d = 0; d < HD; ++d) qreg[d] = qvalid ? qp[d] : 0.f;
    float m = -INFINITY, lsum = 0.f;
    float acc[HD];
    #pragma unroll
    for (int d = 0; d < HD; ++d) acc[d] = 0.f;
    const float scale = 0.17677669529663687f;  // 1/sqrt(32)

    for (int kt = 0; kt < NKT; ++kt) {
        const int k0 = kt << 6;
        __syncthreads();   // previous tile fully consumed (and rl ready on iter 0)
        for (int i = tid; i < 64*8; i += 256) {
            int rr = i >> 3, d4 = i & 7;
            int t = k0 + rr;
            float4 kv, vv;
            if (t < TT) {
                const float* bp = qkv + (size_t)(b*TT + t)*384 + hh*HD + (d4 << 2);
                kv = *reinterpret_cast<const float4*>(bp + 128);
                vv = *reinterpret_cast<const float4*>(bp + 256);
            } else { kv = make_float4(0.f,0.f,0.f,0.f); vv = kv; }
            *reinterpret_cast<float4*>(&Ks[rr][d4 << 2]) = kv;
            *reinterpret_cast<float4*>(&Vs[rr][d4 << 2]) = vv;
        }
        __syncthreads();

        float p[16];
        float mloc = -INFINITY;
        #pragma unroll
        for (int c = 0; c < 16; ++c) {
            int col = (c << 2) + j;   // conflict-free mapping: 4 lanes -> 4 consecutive rows
            float s;
            if (k0 + col < TT) {
                const float4* kp4 = reinterpret_cast<const float4*>(&Ks[col][0]);
                float dot = 0.f;
                #pragma unroll
                for (int d4 = 0; d4 < 8; ++d4) {
                    float4 k4 = kp4[d4];
                    dot = fmaf(qreg[4*d4+0], k4.x, dot);
                    dot = fmaf(qreg[4*d4+1], k4.y, dot);
                    dot = fmaf(qreg[4*d4+2], k4.z, dot);
                    dot = fmaf(qreg[4*d4+3], k4.w, dot);
                }
                s = fmaf(dot, scale, rl[(k0 + col) - tq + (MAXLEN_-1)]);
            } else s = -INFINITY;
            p[c] = s;
            mloc = fmaxf(mloc, s);
        }
        mloc = fmaxf(mloc, __shfl_xor(mloc, 1));
        mloc = fmaxf(mloc, __shfl_xor(mloc, 2));
        float mnew = fmaxf(m, mloc);        // always finite (every tile has valid cols)
        float corr = expf(m - mnew);        // first iter: exp(-inf)=0
        m = mnew;
        float psum = 0.f;
        #pragma unroll
        for (int c = 0; c < 16; ++c) { float e = expf(p[c] - mnew); p[c] = e; psum += e; }
        lsum = lsum * corr + psum;
        #pragma unroll
        for (int d = 0; d < HD; ++d) acc[d] *= corr;
        #pragma unroll
        for (int c = 0; c < 16; ++c) {
            float pc = p[c];
            int col = (c << 2) + j;
            const float4* vp4 = reinterpret_cast<const float4*>(&Vs[col][0]);
            #pragma unroll
            for (int d4 = 0; d4 < 8; ++d4) {
                float4 vv = vp4[d4];
                acc[4*d4+0] = fmaf(pc, vv.x, acc[4*d4+0]);
                acc[4*d4+1] = fmaf(pc, vv.y, acc[4*d4+1]);
                acc[4*d4+2] = fmaf(pc, vv.z, acc[4*d4+2]);
                acc[4*d4+3] = fmaf(pc, vv.w, acc[4*d4+3]);
            }
        }
    }
    lsum += __shfl_xor(lsum, 1);
    lsum += __shfl_xor(lsum, 2);
    #pragma unroll
    for (int d = 0; d < HD; ++d) {
        acc[d] += __shfl_xor(acc[d], 1);
        acc[d] += __shfl_xor(acc[d], 2);
    }
    if (qvalid) {
        float inv = 1.f / lsum;
        #pragma unroll
        for (int dd = 0; dd < 8; ++dd) {
            int d = (j << 3) + dd;
            o[(size_t)(b*TT + tq)*DIM + hh*HD + d] = acc[d] * inv;
        }
    }
}

// ---------------- residual + layernorm: h = LN(h + dlt) ----------------
// one wave per row, lane handles d and d+64
__global__ __launch_bounds__(256) void add_ln_kernel(
    float* __restrict__ h, const float* __restrict__ dlt,
    const float* __restrict__ g, const float* __restrict__ bt)
{
    int wave = threadIdx.x >> 6, lane = threadIdx.x & 63;
    int row = (blockIdx.x << 2) + wave;
    size_t base = (size_t)row * DIM;
    float x0 = h[base + lane]      + dlt[base + lane];
    float x1 = h[base + 64 + lane] + dlt[base + 64 + lane];
    float s = x0 + x1, s2 = x0*x0 + x1*x1;
    #pragma unroll
    for (int off = 1; off < 64; off <<= 1) { s += __shfl_xor(s, off); s2 += __shfl_xor(s2, off); }
    float mean = s * (1.f/128.f);
    float var  = s2 * (1.f/128.f) - mean*mean;
    float rstd = rsqrtf(var + 1e-5f);
    h[base + lane]      = (x0 - mean)*rstd*g[lane]    + bt[lane];
    h[base + 64 + lane] = (x1 - mean)*rstd*g[64+lane] + bt[64+lane];
}

// ---------------- mean-pool + LN + classifier ----------------
__global__ __launch_bounds__(128) void final_kernel(
    const float* __restrict__ h, const float* __restrict__ g,
    const float* __restrict__ bt, const float* __restrict__ cls_w,
    const float* __restrict__ cls_b, float* __restrict__ out)
{
    int b = blockIdx.x, d = threadIdx.x;
    float s = 0.f;
    for (int t = 0; t < TT; ++t) s += h[((size_t)b*TT + t)*DIM + d];
    float pooled = s * (1.f / TT);
    __shared__ float sm[4];
    float v1 = pooled, v2 = pooled * pooled;
    #pragma unroll
    for (int off = 1; off < 64; off <<= 1) { v1 += __shfl_xor(v1, off); v2 += __shfl_xor(v2, off); }
    int wave = threadIdx.x >> 6, lane = threadIdx.x & 63;
    if (lane == 0) { sm[wave*2] = v1; sm[wave*2+1] = v2; }
    __syncthreads();
    float mean = (sm[0] + sm[2]) * (1.f/128.f);
    float var  = (sm[1] + sm[3]) * (1.f/128.f) - mean*mean;
    float xn = (pooled - mean) * rsqrtf(var + 1e-5f) * g[d] + bt[d];
    __shared__ float px[DIM];
    px[d] = xn;
    __syncthreads();
    if (d < NCLS_) {
        float a = cls_b[d];
        for (int i = 0; i < DIM; ++i) a = fmaf(px[i], cls_w[i*NCLS_ + d], a);
        out[b*NCLS_ + d] = a;
    }
}

// ---------------- host ----------------
extern "C" void kernel_launch(void* const* d_in, const int* in_sizes, int n_in,
                              void* d_out, int out_size, void* d_ws, size_t ws_size,
                              hipStream_t stream)
{
    (void)in_sizes; (void)n_in; (void)out_size; (void)ws_size;
    const float* x1      = (const float*)d_in[0];
    const float* proj_w  = (const float*)d_in[1];
    const float* proj_b  = (const float*)d_in[2];
    const float* queries = (const float*)d_in[3];
    const float* fc_w    = (const float*)d_in[4];
    const float* fc_b    = (const float*)d_in[5];
    const float* embed_w = (const float*)d_in[6];
    const float* embed_b = (const float*)d_in[7];
    const float* wqkv    = (const float*)d_in[8];
    const float* bqkv    = (const float*)d_in[9];
    const float* wo      = (const float*)d_in[10];
    const float* bo      = (const float*)d_in[11];
    const float* w1      = (const float*)d_in[12];
    const float* b1      = (const float*)d_in[13];
    const float* w2      = (const float*)d_in[14];
    const float* b2      = (const float*)d_in[15];
    const float* ln1_g   = (const float*)d_in[16];
    const float* ln1_b   = (const float*)d_in[17];
    const float* ln2_g   = (const float*)d_in[18];
    const float* ln2_b   = (const float*)d_in[19];
    const float* rel_t   = (const float*)d_in[20];
    const float* final_g = (const float*)d_in[21];
    const float* final_b = (const float*)d_in[22];
    const float* cls_w   = (const float*)d_in[23];
    const float* cls_b   = (const float*)d_in[24];

    float* ws    = (float*)d_ws;
    float* h     = ws;                            // 16000*128
    float* qkvb  = h     + (size_t)MM*DIM;        // 16000*384 (also reused as tmp 16000x128)
    float* attno = qkvb  + (size_t)MM*384;        // 16000*128
    float* ffm   = attno + (size_t)MM*DIM;        // 16000*512
    float* alpha = ffm   + (size_t)MM*FFD;        // 16
    float* Emat  = alpha + 16;                    // 10*128
    float* c0    = Emat  + QOUT_*DIM;             // 128

    enc_pre_kernel<<<1, 128, 0, stream>>>(proj_w, proj_b, queries, fc_w, fc_b,
                                          embed_w, embed_b, alpha, Emat, c0);
    enc_kernel<<<MM, 64, 0, stream>>>(x1, alpha, Emat, c0, h);

    for (int l = 0; l < NL; ++l) {
        gemm_kernel<<<dim3(384/64, MM/64), 256, 0, stream>>>(
            h, wqkv + (size_t)l*DIM*3*DIM, bqkv + l*3*DIM, qkvb, 384, DIM, 0);
        attn_kernel<<<BB*NHEADS*NKT, 256, 0, stream>>>(
            qkvb, rel_t + l*RELLEN, attno);
        gemm_kernel<<<dim3(DIM/64, MM/64), 256, 0, stream>>>(
            attno, wo + (size_t)l*DIM*DIM, bo + l*DIM, qkvb, DIM, DIM, 0);
        add_ln_kernel<<<MM/4, 256, 0, stream>>>(h, qkvb, ln1_g + l*DIM, ln1_b + l*DIM);
        gemm_kernel<<<dim3(FFD/64, MM/64), 256, 0, stream>>>(
            h, w1 + (size_t)l*DIM*FFD, b1 + l*FFD, ffm, FFD, DIM, 1);
        gemm_kernel<<<dim3(DIM/64, MM/64), 256, 0, stream>>>(
            ffm, w2 + (size_t)l*FFD*DIM, b2 + l*DIM, qkvb, DIM, FFD, 0);
        add_ln_kernel<<<MM/4, 256, 0, stream>>>(h, qkvb, ln2_g + l*DIM, ln2_b + l*DIM);
    }

    final_kernel<<<BB, 128, 0, stream>>>(h, final_g, final_b, cls_w, cls_b, (float*)d_out);
}

// Round 2
// 1144.650 us; speedup vs baseline: 1.7796x; 1.7796x over previous
//
#include <hip/hip_runtime.h>
#include <hip/hip_bf16.h>
#include <cmath>

#define NL      6
#define NHEADS  4
#define DIM     128
#define FFD     512
#define CMID_   8
#define COUT_   16
#define QOUT_   10
#define MAXLEN_ 512
#define NCLS_   3
#define BB      32
#define TT      500
#define FIN_    232
#define MM      (BB*TT)
#define HD      32
#define RELLEN  (2*MAXLEN_-1)

typedef __attribute__((ext_vector_type(8))) short short8;
typedef __attribute__((ext_vector_type(4))) float f32x4;

__device__ inline unsigned bf16r(float x) {   // RNE float->bf16 bits (finite inputs)
    unsigned u = __float_as_uint(x);
    return (u + 0x7fffu + ((u >> 16) & 1u)) >> 16;
}

// ---------------- encoder precompute (1 block) ----------------
__global__ __launch_bounds__(128) void enc_pre_kernel(
    const float* __restrict__ proj_w, const float* __restrict__ proj_b,
    const float* __restrict__ queries, const float* __restrict__ fc_w,
    const float* __restrict__ fc_b, const float* __restrict__ embed_w,
    const float* __restrict__ embed_b,
    float* __restrict__ alpha, float* __restrict__ E, float* __restrict__ c0)
{
    __shared__ float pw[CMID_], cb[CMID_], gam[COUT_], del[COUT_];
    int t = threadIdx.x;
    if (t < CMID_) { pw[t] = proj_w[t]; cb[t] = proj_b[t] + ((t & 1) ? 1.f : 0.f); }
    __syncthreads();
    if (t < QOUT_) {
        float a = 0.f;
        for (int c = 0; c < CMID_; ++c) a += pw[c] * queries[t*CMID_ + c];
        alpha[t] = a;
    }
    if (t < COUT_) {
        float gg = 0.f, dd = 0.f;
        for (int c = 0; c < CMID_; ++c) {
            gg += pw[c] * fc_w[c*COUT_ + t];
            dd += cb[c] * fc_w[c*COUT_ + t];
        }
        gam[t] = gg; del[t] = dd + fc_b[t];
    }
    __syncthreads();
    for (int i = t; i < QOUT_*DIM; i += 128) {
        int q = i / DIM, d = i % DIM;
        float e = 0.f;
        for (int o = 0; o < COUT_; ++o) e += gam[o] * embed_w[(o*QOUT_ + q)*DIM + d];
        E[i] = e;
    }
    {
        float c = embed_b[t];
        for (int o = 0; o < COUT_; ++o) {
            float dl = del[o];
            for (int q = 0; q < QOUT_; ++q) c += dl * embed_w[(o*QOUT_ + q)*DIM + t];
        }
        c0[t] = c;
    }
}

// ---------------- encoder main ----------------
__global__ __launch_bounds__(64) void enc_kernel(
    const float* __restrict__ x1, const float* __restrict__ alpha,
    const float* __restrict__ E, const float* __restrict__ c0,
    float* __restrict__ h)
{
    int bt = blockIdx.x;
    int lane = threadIdx.x;
    const float* xr = x1 + (size_t)bt * FIN_;
    float xv[4];
    bool vld[4];
    #pragma unroll
    for (int i = 0; i < 4; ++i) {
        int f = lane + (i << 6);
        vld[i] = (f < FIN_);
        xv[i] = vld[i] ? xr[f] : 0.f;
    }
    float vmax = -INFINITY, vmin = INFINITY;
    #pragma unroll
    for (int i = 0; i < 4; ++i) if (vld[i]) { vmax = fmaxf(vmax, xv[i]); vmin = fminf(vmin, xv[i]); }
    #pragma unroll
    for (int off = 1; off < 64; off <<= 1) {
        vmax = fmaxf(vmax, __shfl_xor(vmax, off));
        vmin = fminf(vmin, __shfl_xor(vmin, off));
    }
    float mq[QOUT_];
    for (int q = 0; q < QOUT_; ++q) {
        float a = alpha[q];
        float Mx = (a >= 0.f) ? a * vmax : a * vmin;
        float se = 0.f, sx = 0.f;
        #pragma unroll
        for (int i = 0; i < 4; ++i) if (vld[i]) {
            float e = __expf(fmaf(a, xv[i], -Mx));
            se += e; sx += e * xv[i];
        }
        #pragma unroll
        for (int off = 1; off < 64; off <<= 1) { se += __shfl_xor(se, off); sx += __shfl_xor(sx, off); }
        mq[q] = sx / se;
    }
    #pragma unroll
    for (int k = 0; k < 2; ++k) {
        int d = lane + (k << 6);
        float hv = c0[d];
        #pragma unroll
        for (int q = 0; q < QOUT_; ++q) hv = fmaf(mq[q], E[q*DIM + d], hv);
        h[(size_t)bt*DIM + d] = hv;
    }
}

// ---------------- tiled fp32 GEMM (optional bf16 output) ----------------
__global__ __launch_bounds__(256) void gemm_kernel(
    const float* __restrict__ A, const float* __restrict__ W,
    const float* __restrict__ bias, float* __restrict__ C,
    int N, int K, int relu, int obf16)
{
    __shared__ __align__(16) float As[16][68];
    __shared__ __align__(16) float Ws[16][64];
    const int tid = threadIdx.x;
    const int row0 = blockIdx.y << 6;
    const int col0 = blockIdx.x << 6;
    const int tx = tid & 15, ty = tid >> 4;
    const int ar = tid >> 2, ac = (tid & 3) << 2;
    const int wr = tid >> 4, wc = (tid & 15) << 2;
    float acc[4][4] = {};
    for (int k0 = 0; k0 < K; k0 += 16) {
        float4 av = *reinterpret_cast<const float4*>(A + (size_t)(row0 + ar)*K + k0 + ac);
        As[ac+0][ar] = av.x; As[ac+1][ar] = av.y; As[ac+2][ar] = av.z; As[ac+3][ar] = av.w;
        *reinterpret_cast<float4*>(&Ws[wr][wc]) =
            *reinterpret_cast<const float4*>(W + (size_t)(k0 + wr)*N + col0 + wc);
        __syncthreads();
        #pragma unroll
        for (int kk = 0; kk < 16; ++kk) {
            float4 a4 = *reinterpret_cast<const float4*>(&As[kk][ty << 2]);
            float4 b4 = *reinterpret_cast<const float4*>(&Ws[kk][tx << 2]);
            float a[4] = {a4.x, a4.y, a4.z, a4.w};
            float b[4] = {b4.x, b4.y, b4.z, b4.w};
            #pragma unroll
            for (int i = 0; i < 4; ++i)
                #pragma unroll
                for (int j = 0; j < 4; ++j)
                    acc[i][j] = fmaf(a[i], b[j], acc[i][j]);
        }
        __syncthreads();
    }
    #pragma unroll
    for (int i = 0; i < 4; ++i) {
        int r = row0 + (ty << 2) + i;
        #pragma unroll
        for (int j = 0; j < 4; ++j) {
            int c = col0 + (tx << 2) + j;
            float v = acc[i][j] + bias[c];
            if (relu) v = fmaxf(v, 0.f);
            if (obf16) ((unsigned short*)C)[(size_t)r*N + c] = (unsigned short)bf16r(v);
            else       C[(size_t)r*N + c] = v;
        }
    }
}

// ---------------- MFMA bf16 flash attention ----------------
// grid: B*NHEADS*8 blocks, 256 threads = 4 waves x 16 q-rows each.
// qkv: bf16 [b*T+t][384]  (q 0:128 | k 128:256 | v 256:384)
// Swapped QK^T: S^T = K·Q^T so the softmax row (q-row) is lane&15.
__global__ __launch_bounds__(256) void attn_mfma_kernel(
    const unsigned short* __restrict__ qkv, const float* __restrict__ rel,
    float* __restrict__ o)
{
    __shared__ __align__(16) unsigned short Ks[32][40];  // [kcol][dim], 80B rows
    __shared__ __align__(16) unsigned short Vt[32][40];  // [dim][kcol]
    __shared__ float rl[RELLEN];
    const int bid = blockIdx.x;
    const int qt = bid & 7;
    const int bh = bid >> 3;
    const int hh = bh & 3, b = bh >> 2;
    const int tid  = threadIdx.x;
    const int wq   = tid >> 6;
    const int lane = tid & 63;
    const int g = lane >> 4, n = lane & 15;
    for (int i = tid; i < RELLEN; i += 256) rl[i] = rel[i];

    const int qrow = (qt << 6) + (wq << 4) + n;
    const bool qv = (qrow < TT);
    short8 qf = {0,0,0,0,0,0,0,0};
    if (qv) qf = *reinterpret_cast<const short8*>(qkv + (size_t)(b*TT + qrow)*384 + hh*HD + g*8);

    f32x4 acc0 = {0.f,0.f,0.f,0.f}, acc1 = {0.f,0.f,0.f,0.f};
    float m = -INFINITY, lsum = 0.f;
    const float scale = 0.17677669529663687f;   // 1/sqrt(32)
    const f32x4 zf = {0.f,0.f,0.f,0.f};

    for (int kt = 0; kt < 16; ++kt) {
        const int k0 = kt << 5;
        __syncthreads();                    // previous tile consumed (and rl on iter0)
        if (tid < 128) {                    // stage K: [32 cols][32 dims], 16B chunks
            int row = tid >> 2, c = tid & 3;
            int t = k0 + row;
            uint4 val = make_uint4(0,0,0,0);
            if (t < TT) val = *reinterpret_cast<const uint4*>(
                qkv + (size_t)(b*TT + t)*384 + 128 + hh*HD + c*8);
            *reinterpret_cast<uint4*>(&Ks[row][c*8]) = val;
        } else {                            // stage V transposed: Vt[dim][col]
            int i2 = tid - 128;
            int d = i2 & 31, tg = i2 >> 5;  // tg 0..3
            #pragma unroll
            for (int j = 0; j < 8; ++j) {
                int tl = tg*8 + j;
                int t = k0 + tl;
                unsigned short v = 0;
                if (t < TT) v = qkv[(size_t)(b*TT + t)*384 + 256 + hh*HD + d];
                Vt[d][tl] = v;
            }
        }
        __syncthreads();

        // S^T = K · Q^T : A=K-tile (M=16 kcols, K=32 dims), B=Q^T
        short8 ak0 = *reinterpret_cast<const short8*>(&Ks[n][g*8]);
        short8 ak1 = *reinterpret_cast<const short8*>(&Ks[16 + n][g*8]);
        f32x4 s0 = __builtin_amdgcn_mfma_f32_16x16x32_bf16(ak0, qf, zf, 0, 0, 0);
        f32x4 s1 = __builtin_amdgcn_mfma_f32_16x16x32_bf16(ak1, qf, zf, 0, 0, 0);

        // bias + mask + online softmax (row = qrow = lane&15; kcols over g,reg)
        float sv[8];
        float tmax = -INFINITY;
        #pragma unroll
        for (int r = 0; r < 4; ++r) {
            int kc0 = k0 + g*4 + r;
            int kc1 = kc0 + 16;
            float b0 = rl[kc0 - qrow + (MAXLEN_-1)];
            float b1 = rl[kc1 - qrow + (MAXLEN_-1)];
            float v0 = (kc0 < TT) ? fmaf(s0[r], scale, b0) : -1e30f;
            float v1 = (kc1 < TT) ? fmaf(s1[r], scale, b1) : -1e30f;
            sv[r] = v0; sv[4+r] = v1;
            tmax = fmaxf(tmax, fmaxf(v0, v1));
        }
        tmax = fmaxf(tmax, __shfl_xor(tmax, 16));
        tmax = fmaxf(tmax, __shfl_xor(tmax, 32));
        float mnew = fmaxf(m, tmax);
        float corr = __expf(m - mnew);      // first tile: exp(-inf)=0
        m = mnew;
        float ps = 0.f;
        #pragma unroll
        for (int r = 0; r < 8; ++r) { float e = __expf(sv[r] - mnew); sv[r] = e; ps += e; }
        ps += __shfl_xor(ps, 16);
        ps += __shfl_xor(ps, 32);
        lsum = fmaf(lsum, corr, ps);

        // pack P^T -> bf16 pairs (tile0: kcols g*4+r, tile1: +16)
        unsigned pk0lo = bf16r(sv[0]) | (bf16r(sv[1]) << 16);
        unsigned pk0hi = bf16r(sv[2]) | (bf16r(sv[3]) << 16);
        unsigned pk1lo = bf16r(sv[4]) | (bf16r(sv[5]) << 16);
        unsigned pk1hi = bf16r(sv[6]) | (bf16r(sv[7]) << 16);

        // exchange: target lane (group g) needs kcols g*8..g*8+7 for its qrow
        int src0 = n + ((g & 1) << 5);      // lane of source group 2*(g&1)
        int src1 = src0 + 16;
        int t0 = (g < 2);
        unsigned a0 = __shfl((int)pk0lo, src0), c0_ = __shfl((int)pk1lo, src0);
        unsigned a1 = __shfl((int)pk0hi, src0), c1_ = __shfl((int)pk1hi, src0);
        unsigned a2 = __shfl((int)pk0lo, src1), c2_ = __shfl((int)pk1lo, src1);
        unsigned a3 = __shfl((int)pk0hi, src1), c3_ = __shfl((int)pk1hi, src1);
        union { unsigned w[4]; short8 v; } P;
        P.w[0] = t0 ? a0 : c0_;
        P.w[1] = t0 ? a1 : c1_;
        P.w[2] = t0 ? a2 : c2_;
        P.w[3] = t0 ? a3 : c3_;

        // O^T = V^T · P^T : A=V^T halves (M=16 dims, K=32 kcols)
        short8 av0 = *reinterpret_cast<const short8*>(&Vt[n][g*8]);
        short8 av1 = *reinterpret_cast<const short8*>(&Vt[16 + n][g*8]);
        #pragma unroll
        for (int r = 0; r < 4; ++r) { acc0[r] *= corr; acc1[r] *= corr; }
        acc0 = __builtin_amdgcn_mfma_f32_16x16x32_bf16(av0, P.v, acc0, 0, 0, 0);
        acc1 = __builtin_amdgcn_mfma_f32_16x16x32_bf16(av1, P.v, acc1, 0, 0, 0);
    }

    if (qv) {
        float inv = 1.f / lsum;
        #pragma unroll
        for (int r = 0; r < 4; ++r) {
            int d0 = g*4 + r;
            o[(size_t)(b*TT + qrow)*DIM + hh*HD + d0]      = acc0[r] * inv;
            o[(size_t)(b*TT + qrow)*DIM + hh*HD + 16 + d0] = acc1[r] * inv;
        }
    }
}

// ---------------- residual + layernorm ----------------
__global__ __launch_bounds__(256) void add_ln_kernel(
    float* __restrict__ h, const float* __restrict__ dlt,
    const float* __restrict__ g, const float* __restrict__ bt)
{
    int wave = threadIdx.x >> 6, lane = threadIdx.x & 63;
    int row = (blockIdx.x << 2) + wave;
    size_t base = (size_t)row * DIM;
    float x0 = h[base + lane]      + dlt[base + lane];
    float x1 = h[base + 64 + lane] + dlt[base + 64 + lane];
    float s = x0 + x1, s2 = x0*x0 + x1*x1;
    #pragma unroll
    for (int off = 1; off < 64; off <<= 1) { s += __shfl_xor(s, off); s2 += __shfl_xor(s2, off); }
    float mean = s * (1.f/128.f);
    float var  = s2 * (1.f/128.f) - mean*mean;
    float rstd = rsqrtf(var + 1e-5f);
    h[base + lane]      = (x0 - mean)*rstd*g[lane]    + bt[lane];
    h[base + 64 + lane] = (x1 - mean)*rstd*g[64+lane] + bt[64+lane];
}

// ---------------- mean-pool + LN + classifier ----------------
__global__ __launch_bounds__(128) void final_kernel(
    const float* __restrict__ h, const float* __restrict__ g,
    const float* __restrict__ bt, const float* __restrict__ cls_w,
    const float* __restrict__ cls_b, float* __restrict__ out)
{
    int b = blockIdx.x, d = threadIdx.x;
    float s = 0.f;
    for (int t = 0; t < TT; ++t) s += h[((size_t)b*TT + t)*DIM + d];
    float pooled = s * (1.f / TT);
    __shared__ float sm[4];
    float v1 = pooled, v2 = pooled * pooled;
    #pragma unroll
    for (int off = 1; off < 64; off <<= 1) { v1 += __shfl_xor(v1, off); v2 += __shfl_xor(v2, off); }
    int wave = threadIdx.x >> 6, lane = threadIdx.x & 63;
    if (lane == 0) { sm[wave*2] = v1; sm[wave*2+1] = v2; }
    __syncthreads();
    float mean = (sm[0] + sm[2]) * (1.f/128.f);
    float var  = (sm[1] + sm[3]) * (1.f/128.f) - mean*mean;
    float xn = (pooled - mean) * rsqrtf(var + 1e-5f) * g[d] + bt[d];
    __shared__ float px[DIM];
    px[d] = xn;
    __syncthreads();
    if (d < NCLS_) {
        float a = cls_b[d];
        for (int i = 0; i < DIM; ++i) a = fmaf(px[i], cls_w[i*NCLS_ + d], a);
        out[b*NCLS_ + d] = a;
    }
}

// ---------------- host ----------------
extern "C" void kernel_launch(void* const* d_in, const int* in_sizes, int n_in,
                              void* d_out, int out_size, void* d_ws, size_t ws_size,
                              hipStream_t stream)
{
    (void)in_sizes; (void)n_in; (void)out_size; (void)ws_size;
    const float* x1      = (const float*)d_in[0];
    const float* proj_w  = (const float*)d_in[1];
    const float* proj_b  = (const float*)d_in[2];
    const float* queries = (const float*)d_in[3];
    const float* fc_w    = (const float*)d_in[4];
    const float* fc_b    = (const float*)d_in[5];
    const float* embed_w = (const float*)d_in[6];
    const float* embed_b = (const float*)d_in[7];
    const float* wqkv    = (const float*)d_in[8];
    const float* bqkv    = (const float*)d_in[9];
    const float* wo      = (const float*)d_in[10];
    const float* bo      = (const float*)d_in[11];
    const float* w1      = (const float*)d_in[12];
    const float* b1      = (const float*)d_in[13];
    const float* w2      = (const float*)d_in[14];
    const float* b2      = (const float*)d_in[15];
    const float* ln1_g   = (const float*)d_in[16];
    const float* ln1_b   = (const float*)d_in[17];
    const float* ln2_g   = (const float*)d_in[18];
    const float* ln2_b   = (const float*)d_in[19];
    const float* rel_t   = (const float*)d_in[20];
    const float* final_g = (const float*)d_in[21];
    const float* final_b = (const float*)d_in[22];
    const float* cls_w   = (const float*)d_in[23];
    const float* cls_b   = (const float*)d_in[24];

    float* ws    = (float*)d_ws;
    float* h     = ws;                            // 16000*128 f32
    float* qkvb  = h     + (size_t)MM*DIM;        // 16000*384 (bf16 qkv / f32 tmp 16000x128)
    float* attno = qkvb  + (size_t)MM*384;        // 16000*128 f32
    float* ffm   = attno + (size_t)MM*DIM;        // 16000*512 f32
    float* alpha = ffm   + (size_t)MM*FFD;        // 16
    float* Emat  = alpha + 16;                    // 10*128
    float* c0    = Emat  + QOUT_*DIM;             // 128

    enc_pre_kernel<<<1, 128, 0, stream>>>(proj_w, proj_b, queries, fc_w, fc_b,
                                          embed_w, embed_b, alpha, Emat, c0);
    enc_kernel<<<MM, 64, 0, stream>>>(x1, alpha, Emat, c0, h);

    for (int l = 0; l < NL; ++l) {
        // qkv projection -> bf16
        gemm_kernel<<<dim3(384/64, MM/64), 256, 0, stream>>>(
            h, wqkv + (size_t)l*DIM*3*DIM, bqkv + l*3*DIM, qkvb, 384, DIM, 0, 1);
        attn_mfma_kernel<<<BB*NHEADS*8, 256, 0, stream>>>(
            (const unsigned short*)qkvb, rel_t + l*RELLEN, attno);
        gemm_kernel<<<dim3(DIM/64, MM/64), 256, 0, stream>>>(
            attno, wo + (size_t)l*DIM*DIM, bo + l*DIM, qkvb, DIM, DIM, 0, 0);
        add_ln_kernel<<<MM/4, 256, 0, stream>>>(h, qkvb, ln1_g + l*DIM, ln1_b + l*DIM);
        gemm_kernel<<<dim3(FFD/64, MM/64), 256, 0, stream>>>(
            h, w1 + (size_t)l*DIM*FFD, b1 + l*FFD, ffm, FFD, DIM, 1, 0);
        gemm_kernel<<<dim3(DIM/64, MM/64), 256, 0, stream>>>(
            ffm, w2 + (size_t)l*FFD*DIM, b2 + l*DIM, qkvb, DIM, FFD, 0, 0);
        add_ln_kernel<<<MM/4, 256, 0, stream>>>(h, qkvb, ln2_g + l*DIM, ln2_b + l*DIM);
    }

    final_kernel<<<BB, 128, 0, stream>>>(h, final_g, final_b, cls_w, cls_b, (float*)d_out);
}

// Round 3
// 521.633 us; speedup vs baseline: 3.9050x; 2.1944x over previous
//
#include <hip/hip_runtime.h>
#include <hip/hip_bf16.h>
#include <cmath>

#define NL      6
#define NHEADS  4
#define DIM     128
#define FFD     512
#define CMID_   8
#define COUT_   16
#define QOUT_   10
#define MAXLEN_ 512
#define NCLS_   3
#define BB      32
#define TT      500
#define FIN_    232
#define MM      (BB*TT)
#define HD      32
#define RELLEN  (2*MAXLEN_-1)

typedef __attribute__((ext_vector_type(8))) short short8;
typedef __attribute__((ext_vector_type(4))) float f32x4;
typedef unsigned short ushort_t;

__device__ inline unsigned bf16r(float x) {   // RNE float->bf16 bits (finite inputs)
    unsigned u = __float_as_uint(x);
    return (u + 0x7fffu + ((u >> 16) & 1u)) >> 16;
}

// ---------------- encoder precompute (1 block) ----------------
__global__ __launch_bounds__(128) void enc_pre_kernel(
    const float* __restrict__ proj_w, const float* __restrict__ proj_b,
    const float* __restrict__ queries, const float* __restrict__ fc_w,
    const float* __restrict__ fc_b, const float* __restrict__ embed_w,
    const float* __restrict__ embed_b,
    float* __restrict__ alpha, float* __restrict__ E, float* __restrict__ c0)
{
    __shared__ float pw[CMID_], cb[CMID_], gam[COUT_], del[COUT_];
    int t = threadIdx.x;
    if (t < CMID_) { pw[t] = proj_w[t]; cb[t] = proj_b[t] + ((t & 1) ? 1.f : 0.f); }
    __syncthreads();
    if (t < QOUT_) {
        float a = 0.f;
        for (int c = 0; c < CMID_; ++c) a += pw[c] * queries[t*CMID_ + c];
        alpha[t] = a;
    }
    if (t < COUT_) {
        float gg = 0.f, dd = 0.f;
        for (int c = 0; c < CMID_; ++c) {
            gg += pw[c] * fc_w[c*COUT_ + t];
            dd += cb[c] * fc_w[c*COUT_ + t];
        }
        gam[t] = gg; del[t] = dd + fc_b[t];
    }
    __syncthreads();
    for (int i = t; i < QOUT_*DIM; i += 128) {
        int q = i / DIM, d = i % DIM;
        float e = 0.f;
        for (int o = 0; o < COUT_; ++o) e += gam[o] * embed_w[(o*QOUT_ + q)*DIM + d];
        E[i] = e;
    }
    {
        float c = embed_b[t];
        for (int o = 0; o < COUT_; ++o) {
            float dl = del[o];
            for (int q = 0; q < QOUT_; ++q) c += dl * embed_w[(o*QOUT_ + q)*DIM + t];
        }
        c0[t] = c;
    }
}

// ---------------- encoder main ----------------
__global__ __launch_bounds__(64) void enc_kernel(
    const float* __restrict__ x1, const float* __restrict__ alpha,
    const float* __restrict__ E, const float* __restrict__ c0,
    float* __restrict__ h, ushort_t* __restrict__ hb)
{
    int bt = blockIdx.x;
    int lane = threadIdx.x;
    const float* xr = x1 + (size_t)bt * FIN_;
    float xv[4];
    bool vld[4];
    #pragma unroll
    for (int i = 0; i < 4; ++i) {
        int f = lane + (i << 6);
        vld[i] = (f < FIN_);
        xv[i] = vld[i] ? xr[f] : 0.f;
    }
    float vmax = -INFINITY, vmin = INFINITY;
    #pragma unroll
    for (int i = 0; i < 4; ++i) if (vld[i]) { vmax = fmaxf(vmax, xv[i]); vmin = fminf(vmin, xv[i]); }
    #pragma unroll
    for (int off = 1; off < 64; off <<= 1) {
        vmax = fmaxf(vmax, __shfl_xor(vmax, off));
        vmin = fminf(vmin, __shfl_xor(vmin, off));
    }
    float mq[QOUT_];
    for (int q = 0; q < QOUT_; ++q) {
        float a = alpha[q];
        float Mx = (a >= 0.f) ? a * vmax : a * vmin;
        float se = 0.f, sx = 0.f;
        #pragma unroll
        for (int i = 0; i < 4; ++i) if (vld[i]) {
            float e = __expf(fmaf(a, xv[i], -Mx));
            se += e; sx += e * xv[i];
        }
        #pragma unroll
        for (int off = 1; off < 64; off <<= 1) { se += __shfl_xor(se, off); sx += __shfl_xor(sx, off); }
        mq[q] = sx / se;
    }
    #pragma unroll
    for (int k = 0; k < 2; ++k) {
        int d = lane + (k << 6);
        float hv = c0[d];
        #pragma unroll
        for (int q = 0; q < QOUT_; ++q) hv = fmaf(mq[q], E[q*DIM + d], hv);
        h[(size_t)bt*DIM + d] = hv;
        hb[(size_t)bt*DIM + d] = (ushort_t)bf16r(hv);
    }
}

// ---------------- weight transpose + bf16 convert (once per launch) ----------------
// Wt[n][k] = bf16(W[k][n]) for all 4 weight groups, 64x64 tiles, 288 blocks total.
__global__ __launch_bounds__(256) void wtrans_kernel(
    const float* __restrict__ wqkv, const float* __restrict__ wo,
    const float* __restrict__ w1, const float* __restrict__ w2,
    ushort_t* __restrict__ wts)
{
    int bid = blockIdx.x;
    const float* W; ushort_t* Wt; int K, N, tk, tn;
    if (bid < 72) {            // wqkv: K=128,N=384 -> 2x6 tiles x 6 layers
        int l = bid / 12, t = bid % 12; tk = t / 6; tn = t % 6; K = 128; N = 384;
        W = wqkv + (size_t)l*128*384; Wt = wts + (size_t)l*49152;
    } else if (bid < 96) {     // wo: 128x128 -> 2x2 x 6
        int q = bid - 72; int l = q / 4, t = q % 4; tk = t / 2; tn = t % 2; K = 128; N = 128;
        W = wo + (size_t)l*16384; Wt = wts + 294912 + (size_t)l*16384;
    } else if (bid < 192) {    // w1: K=128,N=512 -> 2x8 x 6
        int q = bid - 96; int l = q / 16, t = q % 16; tk = t / 8; tn = t % 8; K = 128; N = 512;
        W = w1 + (size_t)l*65536; Wt = wts + 393216 + (size_t)l*65536;
    } else {                   // w2: K=512,N=128 -> 8x2 x 6
        int q = bid - 192; int l = q / 16, t = q % 16; tk = t / 2; tn = t % 2; K = 512; N = 128;
        W = w2 + (size_t)l*65536; Wt = wts + 786432 + (size_t)l*65536;
    }
    int k0 = tk << 6, n0 = tn << 6;
    __shared__ float Ls[64][65];
    int tid = threadIdx.x;
    #pragma unroll
    for (int i = 0; i < 4; ++i) {
        int id = tid + 256*i;          // 1024 float4-chunks: r=id>>4, ch=id&15
        int r = id >> 4, ch = id & 15;
        float4 v = *reinterpret_cast<const float4*>(W + (size_t)(k0+r)*N + n0 + ch*4);
        Ls[ch*4+0][r] = v.x; Ls[ch*4+1][r] = v.y; Ls[ch*4+2][r] = v.z; Ls[ch*4+3][r] = v.w;
    }
    __syncthreads();
    #pragma unroll
    for (int i = 0; i < 4; ++i) {
        int id = tid + 256*i;
        int rr = id >> 4, ch = id & 15;
        uint2 o2;
        o2.x = bf16r(Ls[rr][ch*4+0]) | (bf16r(Ls[rr][ch*4+1]) << 16);
        o2.y = bf16r(Ls[rr][ch*4+2]) | (bf16r(Ls[rr][ch*4+3]) << 16);
        *reinterpret_cast<uint2*>(Wt + (size_t)(n0+rr)*K + k0 + ch*4) = o2;
    }
}

// ---------------- bf16 MFMA GEMM ----------------
// C[M,N] = A[M,K]@W[K,N] + bias; A bf16 row-major, W given as Wt[N][K] bf16.
// BM x 64 tile, BK=64, 256 threads = 4 waves (wr=w&1 rows BM/2, wc=w>>1 cols 32).
// LDS rows are 128B (64 bf16); chunk-swizzle ^(row&7) -> uniform bank-group spread.
template<int BM>
__global__ __launch_bounds__(256) void gemm_mfma_kernel(
    const ushort_t* __restrict__ A, const ushort_t* __restrict__ Wt,
    const float* __restrict__ bias, void* __restrict__ C,
    int N, int K, int relu, int obf16)
{
    constexpr int MREP = BM / 32;          // m-tiles per wave
    constexpr int APT  = BM / 32;          // A 16B-chunks per thread per stage
    __shared__ __align__(16) ushort_t As[BM * 64];
    __shared__ __align__(16) ushort_t Bs[64 * 64];
    const int tid = threadIdx.x;
    const int row0 = blockIdx.y * BM, col0 = blockIdx.x << 6;
    const int w = tid >> 6, lane = tid & 63, g = lane >> 4, n = lane & 15;
    const int wr = w & 1, wc = w >> 1;
    f32x4 acc[MREP][2];
    #pragma unroll
    for (int mt = 0; mt < MREP; ++mt)
        #pragma unroll
        for (int nt = 0; nt < 2; ++nt) acc[mt][nt] = (f32x4){0.f,0.f,0.f,0.f};

    for (int k0 = 0; k0 < K; k0 += 64) {
        __syncthreads();
        #pragma unroll
        for (int i = 0; i < APT; ++i) {
            int id = tid + 256*i;
            int r = id >> 3, c = id & 7;
            uint4 v = *reinterpret_cast<const uint4*>(A + (size_t)(row0 + r)*K + k0 + c*8);
            *reinterpret_cast<uint4*>(As + r*64 + ((c ^ (r & 7)) << 3)) = v;
        }
        #pragma unroll
        for (int i = 0; i < 2; ++i) {
            int id = tid + 256*i;
            int r = id >> 3, c = id & 7;
            uint4 v = *reinterpret_cast<const uint4*>(Wt + (size_t)(col0 + r)*K + k0 + c*8);
            *reinterpret_cast<uint4*>(Bs + r*64 + ((c ^ (r & 7)) << 3)) = v;
        }
        __syncthreads();
        #pragma unroll
        for (int ks = 0; ks < 2; ++ks) {
            short8 af[MREP], bfr[2];
            #pragma unroll
            for (int mt = 0; mt < MREP; ++mt) {
                int r = wr*(BM/2) + mt*16 + n;
                af[mt] = *reinterpret_cast<const short8*>(As + r*64 + (((ks*4 + g) ^ (r & 7)) << 3));
            }
            #pragma unroll
            for (int nt = 0; nt < 2; ++nt) {
                int r = wc*32 + nt*16 + n;
                bfr[nt] = *reinterpret_cast<const short8*>(Bs + r*64 + (((ks*4 + g) ^ (r & 7)) << 3));
            }
            #pragma unroll
            for (int mt = 0; mt < MREP; ++mt)
                #pragma unroll
                for (int nt = 0; nt < 2; ++nt)
                    acc[mt][nt] = __builtin_amdgcn_mfma_f32_16x16x32_bf16(af[mt], bfr[nt], acc[mt][nt], 0, 0, 0);
        }
    }
    #pragma unroll
    for (int mt = 0; mt < MREP; ++mt) {
        #pragma unroll
        for (int nt = 0; nt < 2; ++nt) {
            int col = col0 + wc*32 + nt*16 + n;
            float bv = bias[col];
            #pragma unroll
            for (int r4 = 0; r4 < 4; ++r4) {
                int row = row0 + wr*(BM/2) + mt*16 + g*4 + r4;
                float v = acc[mt][nt][r4] + bv;
                if (relu) v = fmaxf(v, 0.f);
                if (obf16) ((ushort_t*)C)[(size_t)row*N + col] = (ushort_t)bf16r(v);
                else       ((float*)C)[(size_t)row*N + col] = v;
            }
        }
    }
}

// ---------------- MFMA bf16 flash attention (v2) ----------------
// grid: B*NHEADS*8 blocks, 256 threads = 4 waves x 16 q-rows each.
// qkv: bf16 [b*T+t][384]  (q 0:128 | k 128:256 | v 256:384); o: bf16 [b*T+t][128]
__global__ __launch_bounds__(256) void attn_mfma_kernel(
    const ushort_t* __restrict__ qkv, const float* __restrict__ rel,
    ushort_t* __restrict__ o)
{
    __shared__ __align__(16) ushort_t Ks[32][40];       // [kcol][dim] 80B rows
    __shared__ __align__(16) ushort_t Vs[32][36];       // [kcol][dim] 72B rows
    __shared__ __align__(16) ushort_t VB[2][4][16][8];  // [dimhalf][g][n][j] fragment-linear
    __shared__ float rl[RELLEN];
    const int bid = blockIdx.x;
    const int qt = bid & 7;
    const int bh = bid >> 3;
    const int hh = bh & 3, b = bh >> 2;
    const int tid  = threadIdx.x;
    const int wq   = tid >> 6;
    const int lane = tid & 63;
    const int g = lane >> 4, n = lane & 15;
    for (int i = tid; i < RELLEN; i += 256) rl[i] = rel[i];

    const int qrow = (qt << 6) + (wq << 4) + n;
    const bool qv = (qrow < TT);
    short8 qf = {0,0,0,0,0,0,0,0};
    if (qv) qf = *reinterpret_cast<const short8*>(qkv + (size_t)(b*TT + qrow)*384 + hh*HD + g*8);

    f32x4 acc0 = {0.f,0.f,0.f,0.f}, acc1 = {0.f,0.f,0.f,0.f};
    float m = -INFINITY, lsum = 0.f;
    const float scale = 0.17677669529663687f;   // 1/sqrt(32)
    const f32x4 zf = {0.f,0.f,0.f,0.f};

    // staging ids: 256 threads: tid<128 stage K rows, else V rows (coalesced uint4)
    const int sr = (tid & 127) >> 2, sc = tid & 3;

    for (int kt = 0; kt < 16; ++kt) {
        const int k0 = kt << 5;
        __syncthreads();                    // prev tile fully consumed
        {
            int t = k0 + sr;
            uint4 val = make_uint4(0,0,0,0);
            if (t < TT) val = *reinterpret_cast<const uint4*>(
                qkv + (size_t)(b*TT + t)*384 + ((tid < 128) ? 128 : 256) + hh*HD + sc*8);
            if (tid < 128) {
                *reinterpret_cast<uint4*>(&Ks[sr][sc*8]) = val;
            } else {
                uint2 lo = make_uint2(val.x, val.y), hi = make_uint2(val.z, val.w);
                *reinterpret_cast<uint2*>(&Vs[sr][sc*8])     = lo;
                *reinterpret_cast<uint2*>(&Vs[sr][sc*8 + 4]) = hi;
            }
        }
        __syncthreads();

        // V relayout into fragment-linear VB (overlapped with QK^T+softmax below)
        if (tid < 128) {
            int half = tid >> 6, gg = (tid >> 4) & 3, nn = tid & 15;
            ushort_t tmp[8];
            #pragma unroll
            for (int j = 0; j < 8; ++j) tmp[j] = Vs[gg*8 + j][half*16 + nn];
            *reinterpret_cast<uint4*>(&VB[half][gg][nn][0]) = *reinterpret_cast<uint4*>(tmp);
        }

        // S^T = K · Q^T
        short8 ak0 = *reinterpret_cast<const short8*>(&Ks[n][g*8]);
        short8 ak1 = *reinterpret_cast<const short8*>(&Ks[16 + n][g*8]);
        f32x4 s0 = __builtin_amdgcn_mfma_f32_16x16x32_bf16(ak0, qf, zf, 0, 0, 0);
        f32x4 s1 = __builtin_amdgcn_mfma_f32_16x16x32_bf16(ak1, qf, zf, 0, 0, 0);

        // bias + mask + online softmax (row = qrow = lane&15)
        float sv[8];
        float tmax = -INFINITY;
        #pragma unroll
        for (int r = 0; r < 4; ++r) {
            int kc0 = k0 + g*4 + r;
            int kc1 = kc0 + 16;
            float b0 = rl[kc0 - qrow + (MAXLEN_-1)];
            float b1 = rl[kc1 - qrow + (MAXLEN_-1)];
            float v0 = (kc0 < TT) ? fmaf(s0[r], scale, b0) : -1e30f;
            float v1 = (kc1 < TT) ? fmaf(s1[r], scale, b1) : -1e30f;
            sv[r] = v0; sv[4+r] = v1;
            tmax = fmaxf(tmax, fmaxf(v0, v1));
        }
        tmax = fmaxf(tmax, __shfl_xor(tmax, 16));
        tmax = fmaxf(tmax, __shfl_xor(tmax, 32));
        float mnew = fmaxf(m, tmax);
        float corr = __expf(m - mnew);
        m = mnew;
        float ps = 0.f;
        #pragma unroll
        for (int r = 0; r < 8; ++r) { float e = __expf(sv[r] - mnew); sv[r] = e; ps += e; }
        ps += __shfl_xor(ps, 16);
        ps += __shfl_xor(ps, 32);
        lsum = fmaf(lsum, corr, ps);

        // pack P^T -> bf16, exchange so lane holds P[qrow=n][kcol=g*8+j]
        unsigned pk0lo = bf16r(sv[0]) | (bf16r(sv[1]) << 16);
        unsigned pk0hi = bf16r(sv[2]) | (bf16r(sv[3]) << 16);
        unsigned pk1lo = bf16r(sv[4]) | (bf16r(sv[5]) << 16);
        unsigned pk1hi = bf16r(sv[6]) | (bf16r(sv[7]) << 16);
        int src0 = n + ((g & 1) << 5);
        int src1 = src0 + 16;
        int t0 = (g < 2);
        unsigned a0 = __shfl((int)pk0lo, src0), c0_ = __shfl((int)pk1lo, src0);
        unsigned a1 = __shfl((int)pk0hi, src0), c1_ = __shfl((int)pk1hi, src0);
        unsigned a2 = __shfl((int)pk0lo, src1), c2_ = __shfl((int)pk1lo, src1);
        unsigned a3 = __shfl((int)pk0hi, src1), c3_ = __shfl((int)pk1hi, src1);
        union { unsigned wd[4]; short8 v; } P;
        P.wd[0] = t0 ? a0 : c0_;
        P.wd[1] = t0 ? a1 : c1_;
        P.wd[2] = t0 ? a2 : c2_;
        P.wd[3] = t0 ? a3 : c3_;

        __syncthreads();                    // VB ready
        short8 av0 = *reinterpret_cast<const short8*>(&VB[0][g][n][0]);
        short8 av1 = *reinterpret_cast<const short8*>(&VB[1][g][n][0]);
        #pragma unroll
        for (int r = 0; r < 4; ++r) { acc0[r] *= corr; acc1[r] *= corr; }
        acc0 = __builtin_amdgcn_mfma_f32_16x16x32_bf16(av0, P.v, acc0, 0, 0, 0);
        acc1 = __builtin_amdgcn_mfma_f32_16x16x32_bf16(av1, P.v, acc1, 0, 0, 0);
    }

    if (qv) {
        float inv = 1.f / lsum;
        #pragma unroll
        for (int r = 0; r < 4; ++r) {
            int d0 = g*4 + r;
            o[(size_t)(b*TT + qrow)*DIM + hh*HD + d0]      = (ushort_t)bf16r(acc0[r] * inv);
            o[(size_t)(b*TT + qrow)*DIM + hh*HD + 16 + d0] = (ushort_t)bf16r(acc1[r] * inv);
        }
    }
}

// ---------------- residual + layernorm (writes fp32 h and bf16 shadow) ----------------
__global__ __launch_bounds__(256) void add_ln_kernel(
    float* __restrict__ h, ushort_t* __restrict__ hb, const float* __restrict__ dlt,
    const float* __restrict__ g, const float* __restrict__ bt)
{
    int wave = threadIdx.x >> 6, lane = threadIdx.x & 63;
    int row = (blockIdx.x << 2) + wave;
    size_t base = (size_t)row * DIM;
    float x0 = h[base + lane]      + dlt[base + lane];
    float x1 = h[base + 64 + lane] + dlt[base + 64 + lane];
    float s = x0 + x1, s2 = x0*x0 + x1*x1;
    #pragma unroll
    for (int off = 1; off < 64; off <<= 1) { s += __shfl_xor(s, off); s2 += __shfl_xor(s2, off); }
    float mean = s * (1.f/128.f);
    float var  = s2 * (1.f/128.f) - mean*mean;
    float rstd = rsqrtf(var + 1e-5f);
    float y0 = (x0 - mean)*rstd*g[lane]    + bt[lane];
    float y1 = (x1 - mean)*rstd*g[64+lane] + bt[64+lane];
    h[base + lane]       = y0;
    h[base + 64 + lane]  = y1;
    hb[base + lane]      = (ushort_t)bf16r(y0);
    hb[base + 64 + lane] = (ushort_t)bf16r(y1);
}

// ---------------- mean-pool + LN + classifier ----------------
__global__ __launch_bounds__(128) void final_kernel(
    const float* __restrict__ h, const float* __restrict__ g,
    const float* __restrict__ bt, const float* __restrict__ cls_w,
    const float* __restrict__ cls_b, float* __restrict__ out)
{
    int b = blockIdx.x, d = threadIdx.x;
    float s = 0.f;
    for (int t = 0; t < TT; ++t) s += h[((size_t)b*TT + t)*DIM + d];
    float pooled = s * (1.f / TT);
    __shared__ float sm[4];
    float v1 = pooled, v2 = pooled * pooled;
    #pragma unroll
    for (int off = 1; off < 64; off <<= 1) { v1 += __shfl_xor(v1, off); v2 += __shfl_xor(v2, off); }
    int wave = threadIdx.x >> 6, lane = threadIdx.x & 63;
    if (lane == 0) { sm[wave*2] = v1; sm[wave*2+1] = v2; }
    __syncthreads();
    float mean = (sm[0] + sm[2]) * (1.f/128.f);
    float var  = (sm[1] + sm[3]) * (1.f/128.f) - mean*mean;
    float xn = (pooled - mean) * rsqrtf(var + 1e-5f) * g[d] + bt[d];
    __shared__ float px[DIM];
    px[d] = xn;
    __syncthreads();
    if (d < NCLS_) {
        float a = cls_b[d];
        for (int i = 0; i < DIM; ++i) a = fmaf(px[i], cls_w[i*NCLS_ + d], a);
        out[b*NCLS_ + d] = a;
    }
}

// ---------------- host ----------------
extern "C" void kernel_launch(void* const* d_in, const int* in_sizes, int n_in,
                              void* d_out, int out_size, void* d_ws, size_t ws_size,
                              hipStream_t stream)
{
    (void)in_sizes; (void)n_in; (void)out_size; (void)ws_size;
    const float* x1      = (const float*)d_in[0];
    const float* proj_w  = (const float*)d_in[1];
    const float* proj_b  = (const float*)d_in[2];
    const float* queries = (const float*)d_in[3];
    const float* fc_w    = (const float*)d_in[4];
    const float* fc_b    = (const float*)d_in[5];
    const float* embed_w = (const float*)d_in[6];
    const float* embed_b = (const float*)d_in[7];
    const float* wqkv    = (const float*)d_in[8];
    const float* bqkv    = (const float*)d_in[9];
    const float* wo      = (const float*)d_in[10];
    const float* bo      = (const float*)d_in[11];
    const float* w1      = (const float*)d_in[12];
    const float* b1      = (const float*)d_in[13];
    const float* w2      = (const float*)d_in[14];
    const float* b2      = (const float*)d_in[15];
    const float* ln1_g   = (const float*)d_in[16];
    const float* ln1_b   = (const float*)d_in[17];
    const float* ln2_g   = (const float*)d_in[18];
    const float* ln2_b   = (const float*)d_in[19];
    const float* rel_t   = (const float*)d_in[20];
    const float* final_g = (const float*)d_in[21];
    const float* final_b = (const float*)d_in[22];
    const float* cls_w   = (const float*)d_in[23];
    const float* cls_b   = (const float*)d_in[24];

    float* ws     = (float*)d_ws;
    float* h      = ws;                               // MM*128 f32
    float* delta  = h + (size_t)MM*DIM;               // MM*128 f32
    ushort_t* hb    = (ushort_t*)(delta + (size_t)MM*DIM); // MM*128 bf16
    ushort_t* qkvb  = hb    + (size_t)MM*DIM;         // MM*384 bf16
    ushort_t* attno = qkvb  + (size_t)MM*384;         // MM*128 bf16
    ushort_t* ffm   = attno + (size_t)MM*DIM;         // MM*512 bf16
    ushort_t* wts   = ffm   + (size_t)MM*FFD;         // 1179648 bf16
    float* alpha  = (float*)(wts + 1179648);          // 16
    float* Emat   = alpha + 16;                       // 10*128
    float* c0     = Emat + QOUT_*DIM;                 // 128

    enc_pre_kernel<<<1, 128, 0, stream>>>(proj_w, proj_b, queries, fc_w, fc_b,
                                          embed_w, embed_b, alpha, Emat, c0);
    wtrans_kernel<<<288, 256, 0, stream>>>(wqkv, wo, w1, w2, wts);
    enc_kernel<<<MM, 64, 0, stream>>>(x1, alpha, Emat, c0, h, hb);

    for (int l = 0; l < NL; ++l) {
        const ushort_t* wqkv_t = wts + (size_t)l*49152;
        const ushort_t* wo_t   = wts + 294912 + (size_t)l*16384;
        const ushort_t* w1_t   = wts + 393216 + (size_t)l*65536;
        const ushort_t* w2_t   = wts + 786432 + (size_t)l*65536;

        gemm_mfma_kernel<128><<<dim3(384/64, MM/128), 256, 0, stream>>>(
            hb, wqkv_t, bqkv + l*3*DIM, qkvb, 384, DIM, 0, 1);
        attn_mfma_kernel<<<BB*NHEADS*8, 256, 0, stream>>>(
            qkvb, rel_t + l*RELLEN, attno);
        gemm_mfma_kernel<64><<<dim3(DIM/64, MM/64), 256, 0, stream>>>(
            attno, wo_t, bo + l*DIM, delta, DIM, DIM, 0, 0);
        add_ln_kernel<<<MM/4, 256, 0, stream>>>(h, hb, delta, ln1_g + l*DIM, ln1_b + l*DIM);
        gemm_mfma_kernel<128><<<dim3(FFD/64, MM/128), 256, 0, stream>>>(
            hb, w1_t, b1 + l*FFD, ffm, FFD, DIM, 1, 1);
        gemm_mfma_kernel<64><<<dim3(DIM/64, MM/64), 256, 0, stream>>>(
            ffm, w2_t, b2 + l*DIM, delta, DIM, FFD, 0, 0);
        add_ln_kernel<<<MM/4, 256, 0, stream>>>(h, hb, delta, ln2_g + l*DIM, ln2_b + l*DIM);
    }

    final_kernel<<<BB, 128, 0, stream>>>(h, final_g, final_b, cls_w, cls_b, (float*)d_out);
}

// Round 4
// 459.368 us; speedup vs baseline: 4.4344x; 1.1355x over previous
//
#include <hip/hip_runtime.h>
#include <hip/hip_bf16.h>
#include <cmath>

#define NL      6
#define NHEADS  4
#define DIM     128
#define FFD     512
#define CMID_   8
#define COUT_   16
#define QOUT_   10
#define MAXLEN_ 512
#define NCLS_   3
#define BB      32
#define TT      500
#define FIN_    232
#define MM      (BB*TT)
#define HD      32
#define RELLEN  (2*MAXLEN_-1)

typedef __attribute__((ext_vector_type(8))) short short8;
typedef __attribute__((ext_vector_type(4))) float f32x4;
typedef unsigned short ushort_t;

__device__ inline unsigned bf16r(float x) {   // RNE float->bf16 bits (finite inputs)
    unsigned u = __float_as_uint(x);
    return (u + 0x7fffu + ((u >> 16) & 1u)) >> 16;
}

// ---------------- encoder precompute (1 block) ----------------
__global__ __launch_bounds__(128) void enc_pre_kernel(
    const float* __restrict__ proj_w, const float* __restrict__ proj_b,
    const float* __restrict__ queries, const float* __restrict__ fc_w,
    const float* __restrict__ fc_b, const float* __restrict__ embed_w,
    const float* __restrict__ embed_b,
    float* __restrict__ alpha, float* __restrict__ E, float* __restrict__ c0)
{
    __shared__ float pw[CMID_], cb[CMID_], gam[COUT_], del[COUT_];
    int t = threadIdx.x;
    if (t < CMID_) { pw[t] = proj_w[t]; cb[t] = proj_b[t] + ((t & 1) ? 1.f : 0.f); }
    __syncthreads();
    if (t < QOUT_) {
        float a = 0.f;
        for (int c = 0; c < CMID_; ++c) a += pw[c] * queries[t*CMID_ + c];
        alpha[t] = a;
    }
    if (t < COUT_) {
        float gg = 0.f, dd = 0.f;
        for (int c = 0; c < CMID_; ++c) {
            gg += pw[c] * fc_w[c*COUT_ + t];
            dd += cb[c] * fc_w[c*COUT_ + t];
        }
        gam[t] = gg; del[t] = dd + fc_b[t];
    }
    __syncthreads();
    for (int i = t; i < QOUT_*DIM; i += 128) {
        int q = i / DIM, d = i % DIM;
        float e = 0.f;
        for (int o = 0; o < COUT_; ++o) e += gam[o] * embed_w[(o*QOUT_ + q)*DIM + d];
        E[i] = e;
    }
    {
        float c = embed_b[t];
        for (int o = 0; o < COUT_; ++o) {
            float dl = del[o];
            for (int q = 0; q < QOUT_; ++q) c += dl * embed_w[(o*QOUT_ + q)*DIM + t];
        }
        c0[t] = c;
    }
}

// ---------------- encoder main ----------------
__global__ __launch_bounds__(64) void enc_kernel(
    const float* __restrict__ x1, const float* __restrict__ alpha,
    const float* __restrict__ E, const float* __restrict__ c0,
    float* __restrict__ h, ushort_t* __restrict__ hb)
{
    int bt = blockIdx.x;
    int lane = threadIdx.x;
    const float* xr = x1 + (size_t)bt * FIN_;
    float xv[4];
    bool vld[4];
    #pragma unroll
    for (int i = 0; i < 4; ++i) {
        int f = lane + (i << 6);
        vld[i] = (f < FIN_);
        xv[i] = vld[i] ? xr[f] : 0.f;
    }
    float vmax = -INFINITY, vmin = INFINITY;
    #pragma unroll
    for (int i = 0; i < 4; ++i) if (vld[i]) { vmax = fmaxf(vmax, xv[i]); vmin = fminf(vmin, xv[i]); }
    #pragma unroll
    for (int off = 1; off < 64; off <<= 1) {
        vmax = fmaxf(vmax, __shfl_xor(vmax, off));
        vmin = fminf(vmin, __shfl_xor(vmin, off));
    }
    float mq[QOUT_];
    for (int q = 0; q < QOUT_; ++q) {
        float a = alpha[q];
        float Mx = (a >= 0.f) ? a * vmax : a * vmin;
        float se = 0.f, sx = 0.f;
        #pragma unroll
        for (int i = 0; i < 4; ++i) if (vld[i]) {
            float e = __expf(fmaf(a, xv[i], -Mx));
            se += e; sx += e * xv[i];
        }
        #pragma unroll
        for (int off = 1; off < 64; off <<= 1) { se += __shfl_xor(se, off); sx += __shfl_xor(sx, off); }
        mq[q] = sx / se;
    }
    #pragma unroll
    for (int k = 0; k < 2; ++k) {
        int d = lane + (k << 6);
        float hv = c0[d];
        #pragma unroll
        for (int q = 0; q < QOUT_; ++q) hv = fmaf(mq[q], E[q*DIM + d], hv);
        h[(size_t)bt*DIM + d] = hv;
        hb[(size_t)bt*DIM + d] = (ushort_t)bf16r(hv);
    }
}

// ---------------- weight transpose + bf16 convert (once per launch) ----------------
__global__ __launch_bounds__(256) void wtrans_kernel(
    const float* __restrict__ wqkv, const float* __restrict__ wo,
    const float* __restrict__ w1, const float* __restrict__ w2,
    ushort_t* __restrict__ wts)
{
    int bid = blockIdx.x;
    const float* W; ushort_t* Wt; int K, N, tk, tn;
    if (bid < 72) {            // wqkv: K=128,N=384 -> 2x6 tiles x 6 layers
        int l = bid / 12, t = bid % 12; tk = t / 6; tn = t % 6; K = 128; N = 384;
        W = wqkv + (size_t)l*128*384; Wt = wts + (size_t)l*49152;
    } else if (bid < 96) {     // wo: 128x128 -> 2x2 x 6
        int q = bid - 72; int l = q / 4, t = q % 4; tk = t / 2; tn = t % 2; K = 128; N = 128;
        W = wo + (size_t)l*16384; Wt = wts + 294912 + (size_t)l*16384;
    } else if (bid < 192) {    // w1: K=128,N=512 -> 2x8 x 6
        int q = bid - 96; int l = q / 16, t = q % 16; tk = t / 8; tn = t % 8; K = 128; N = 512;
        W = w1 + (size_t)l*65536; Wt = wts + 393216 + (size_t)l*65536;
    } else {                   // w2: K=512,N=128 -> 8x2 x 6
        int q = bid - 192; int l = q / 16, t = q % 16; tk = t / 2; tn = t % 2; K = 512; N = 128;
        W = w2 + (size_t)l*65536; Wt = wts + 786432 + (size_t)l*65536;
    }
    int k0 = tk << 6, n0 = tn << 6;
    __shared__ float Ls[64][65];
    int tid = threadIdx.x;
    #pragma unroll
    for (int i = 0; i < 4; ++i) {
        int id = tid + 256*i;
        int r = id >> 4, ch = id & 15;
        float4 v = *reinterpret_cast<const float4*>(W + (size_t)(k0+r)*N + n0 + ch*4);
        Ls[ch*4+0][r] = v.x; Ls[ch*4+1][r] = v.y; Ls[ch*4+2][r] = v.z; Ls[ch*4+3][r] = v.w;
    }
    __syncthreads();
    #pragma unroll
    for (int i = 0; i < 4; ++i) {
        int id = tid + 256*i;
        int rr = id >> 4, ch = id & 15;
        uint2 o2;
        o2.x = bf16r(Ls[rr][ch*4+0]) | (bf16r(Ls[rr][ch*4+1]) << 16);
        o2.y = bf16r(Ls[rr][ch*4+2]) | (bf16r(Ls[rr][ch*4+3]) << 16);
        *reinterpret_cast<uint2*>(Wt + (size_t)(n0+rr)*K + k0 + ch*4) = o2;
    }
}

// ---------------- bf16 MFMA GEMM (qkv / w1) ----------------
template<int BM>
__global__ __launch_bounds__(256) void gemm_mfma_kernel(
    const ushort_t* __restrict__ A, const ushort_t* __restrict__ Wt,
    const float* __restrict__ bias, void* __restrict__ C,
    int N, int K, int relu, int obf16)
{
    constexpr int MREP = BM / 32;
    constexpr int APT  = BM / 32;
    __shared__ __align__(16) ushort_t As[BM * 64];
    __shared__ __align__(16) ushort_t Bs[64 * 64];
    const int tid = threadIdx.x;
    const int row0 = blockIdx.y * BM, col0 = blockIdx.x << 6;
    const int w = tid >> 6, lane = tid & 63, g = lane >> 4, n = lane & 15;
    const int wr = w & 1, wc = w >> 1;
    f32x4 acc[MREP][2];
    #pragma unroll
    for (int mt = 0; mt < MREP; ++mt)
        #pragma unroll
        for (int nt = 0; nt < 2; ++nt) acc[mt][nt] = (f32x4){0.f,0.f,0.f,0.f};

    for (int k0 = 0; k0 < K; k0 += 64) {
        __syncthreads();
        #pragma unroll
        for (int i = 0; i < APT; ++i) {
            int id = tid + 256*i;
            int r = id >> 3, c = id & 7;
            uint4 v = *reinterpret_cast<const uint4*>(A + (size_t)(row0 + r)*K + k0 + c*8);
            *reinterpret_cast<uint4*>(As + r*64 + ((c ^ (r & 7)) << 3)) = v;
        }
        #pragma unroll
        for (int i = 0; i < 2; ++i) {
            int id = tid + 256*i;
            int r = id >> 3, c = id & 7;
            uint4 v = *reinterpret_cast<const uint4*>(Wt + (size_t)(col0 + r)*K + k0 + c*8);
            *reinterpret_cast<uint4*>(Bs + r*64 + ((c ^ (r & 7)) << 3)) = v;
        }
        __syncthreads();
        #pragma unroll
        for (int ks = 0; ks < 2; ++ks) {
            short8 af[MREP], bfr[2];
            #pragma unroll
            for (int mt = 0; mt < MREP; ++mt) {
                int r = wr*(BM/2) + mt*16 + n;
                af[mt] = *reinterpret_cast<const short8*>(As + r*64 + (((ks*4 + g) ^ (r & 7)) << 3));
            }
            #pragma unroll
            for (int nt = 0; nt < 2; ++nt) {
                int r = wc*32 + nt*16 + n;
                bfr[nt] = *reinterpret_cast<const short8*>(Bs + r*64 + (((ks*4 + g) ^ (r & 7)) << 3));
            }
            #pragma unroll
            for (int mt = 0; mt < MREP; ++mt)
                #pragma unroll
                for (int nt = 0; nt < 2; ++nt)
                    acc[mt][nt] = __builtin_amdgcn_mfma_f32_16x16x32_bf16(af[mt], bfr[nt], acc[mt][nt], 0, 0, 0);
        }
    }
    #pragma unroll
    for (int mt = 0; mt < MREP; ++mt) {
        #pragma unroll
        for (int nt = 0; nt < 2; ++nt) {
            int col = col0 + wc*32 + nt*16 + n;
            float bv = bias[col];
            #pragma unroll
            for (int r4 = 0; r4 < 4; ++r4) {
                int row = row0 + wr*(BM/2) + mt*16 + g*4 + r4;
                float v = acc[mt][nt][r4] + bv;
                if (relu) v = fmaxf(v, 0.f);
                if (obf16) ((ushort_t*)C)[(size_t)row*N + col] = (ushort_t)bf16r(v);
                else       ((float*)C)[(size_t)row*N + col] = v;
            }
        }
    }
}

// ---------------- fused GEMM + bias + residual + LayerNorm (wo / w2 path) ----------------
// C_pre[M,128] = A[M,K]@W[K,128] + bias;  h = LN(h + C_pre);  hb = bf16(h)
// BM=32, BN=128 (full rows per block). 256 threads = 4 waves, wave w owns cols w*32..w*32+31.
__global__ __launch_bounds__(256) void gemm_ln_kernel(
    const ushort_t* __restrict__ A, const ushort_t* __restrict__ Wt,
    const float* __restrict__ bias, float* __restrict__ h, ushort_t* __restrict__ hb,
    const float* __restrict__ lng, const float* __restrict__ lnb, int K)
{
    __shared__ __align__(16) ushort_t As[32 * 64];
    __shared__ __align__(16) ushort_t Bs[128 * 64];
    __shared__ float red[4][32][2];
    __shared__ float stats[32][2];
    const int tid = threadIdx.x;
    const int row0 = blockIdx.x << 5;
    const int wc = tid >> 6, lane = tid & 63, g = lane >> 4, n = lane & 15;
    f32x4 acc[2][2];
    #pragma unroll
    for (int mt = 0; mt < 2; ++mt)
        #pragma unroll
        for (int nt = 0; nt < 2; ++nt) acc[mt][nt] = (f32x4){0.f,0.f,0.f,0.f};

    for (int k0 = 0; k0 < K; k0 += 64) {
        __syncthreads();
        {   // A: 32 rows x 8 chunks = 256
            int r = tid >> 3, c = tid & 7;
            uint4 v = *reinterpret_cast<const uint4*>(A + (size_t)(row0 + r)*K + k0 + c*8);
            *reinterpret_cast<uint4*>(As + r*64 + ((c ^ (r & 7)) << 3)) = v;
        }
        #pragma unroll
        for (int i = 0; i < 4; ++i) {   // B: 128 rows x 8 chunks = 1024
            int id = tid + 256*i;
            int r = id >> 3, c = id & 7;
            uint4 v = *reinterpret_cast<const uint4*>(Wt + (size_t)r*K + k0 + c*8);
            *reinterpret_cast<uint4*>(Bs + r*64 + ((c ^ (r & 7)) << 3)) = v;
        }
        __syncthreads();
        #pragma unroll
        for (int ks = 0; ks < 2; ++ks) {
            short8 af[2], bfr[2];
            #pragma unroll
            for (int mt = 0; mt < 2; ++mt) {
                int r = mt*16 + n;
                af[mt] = *reinterpret_cast<const short8*>(As + r*64 + (((ks*4 + g) ^ (r & 7)) << 3));
            }
            #pragma unroll
            for (int nt = 0; nt < 2; ++nt) {
                int r = wc*32 + nt*16 + n;
                bfr[nt] = *reinterpret_cast<const short8*>(Bs + r*64 + (((ks*4 + g) ^ (r & 7)) << 3));
            }
            #pragma unroll
            for (int mt = 0; mt < 2; ++mt)
                #pragma unroll
                for (int nt = 0; nt < 2; ++nt)
                    acc[mt][nt] = __builtin_amdgcn_mfma_f32_16x16x32_bf16(af[mt], bfr[nt], acc[mt][nt], 0, 0, 0);
        }
    }

    // epilogue: vals = acc + bias + resid(h)
    float vals[2][2][4];
    #pragma unroll
    for (int nt = 0; nt < 2; ++nt) {
        int col = wc*32 + nt*16 + n;
        float bv = bias[col];
        #pragma unroll
        for (int mt = 0; mt < 2; ++mt)
            #pragma unroll
            for (int r4 = 0; r4 < 4; ++r4) {
                int row = row0 + mt*16 + g*4 + r4;
                vals[mt][nt][r4] = acc[mt][nt][r4] + bv + h[(size_t)row*DIM + col];
            }
    }
    // per-row partial sums over this wave's 32 cols, reduce over n-lanes
    #pragma unroll
    for (int mt = 0; mt < 2; ++mt)
        #pragma unroll
        for (int r4 = 0; r4 < 4; ++r4) {
            float s  = vals[mt][0][r4] + vals[mt][1][r4];
            float s2 = vals[mt][0][r4]*vals[mt][0][r4] + vals[mt][1][r4]*vals[mt][1][r4];
            #pragma unroll
            for (int off = 1; off < 16; off <<= 1) {
                s  += __shfl_xor(s, off);
                s2 += __shfl_xor(s2, off);
            }
            if (n == 0) { red[wc][mt*16 + g*4 + r4][0] = s; red[wc][mt*16 + g*4 + r4][1] = s2; }
        }
    __syncthreads();
    if (tid < 32) {
        float s = 0.f, s2 = 0.f;
        #pragma unroll
        for (int ww = 0; ww < 4; ++ww) { s += red[ww][tid][0]; s2 += red[ww][tid][1]; }
        float mean = s * (1.f/128.f);
        float var  = s2 * (1.f/128.f) - mean*mean;
        stats[tid][0] = mean;
        stats[tid][1] = rsqrtf(var + 1e-5f);
    }
    __syncthreads();
    #pragma unroll
    for (int nt = 0; nt < 2; ++nt) {
        int col = wc*32 + nt*16 + n;
        float gv = lng[col], bv = lnb[col];
        #pragma unroll
        for (int mt = 0; mt < 2; ++mt)
            #pragma unroll
            for (int r4 = 0; r4 < 4; ++r4) {
                int rloc = mt*16 + g*4 + r4;
                int row = row0 + rloc;
                float y = (vals[mt][nt][r4] - stats[rloc][0]) * stats[rloc][1] * gv + bv;
                h[(size_t)row*DIM + col]  = y;
                hb[(size_t)row*DIM + col] = (ushort_t)bf16r(y);
            }
    }
}

// ---------------- MFMA bf16 flash attention (KVBLK=64) ----------------
// grid: B*NHEADS*8 blocks, 256 threads = 4 waves x 16 q-rows each.
__global__ __launch_bounds__(256) void attn_mfma_kernel(
    const ushort_t* __restrict__ qkv, const float* __restrict__ rel,
    ushort_t* __restrict__ o)
{
    __shared__ __align__(16) ushort_t Ks[64][40];          // [kcol][dim] 80B rows
    __shared__ __align__(16) ushort_t Vs[64][36];          // [kcol][dim] 72B rows
    __shared__ __align__(16) ushort_t VB[2][2][4][16][8];  // [kchalf][dimhalf][g][n][j]
    __shared__ float rl[RELLEN];
    const int bid = blockIdx.x;
    const int qt = bid & 7;
    const int bh = bid >> 3;
    const int hh = bh & 3, b = bh >> 2;
    const int tid  = threadIdx.x;
    const int wq   = tid >> 6;
    const int lane = tid & 63;
    const int g = lane >> 4, n = lane & 15;
    for (int i = tid; i < RELLEN; i += 256) rl[i] = rel[i];

    const int qrow = (qt << 6) + (wq << 4) + n;
    const bool qv = (qrow < TT);
    short8 qf = {0,0,0,0,0,0,0,0};
    if (qv) qf = *reinterpret_cast<const short8*>(qkv + (size_t)(b*TT + qrow)*384 + hh*HD + g*8);

    f32x4 acc0 = {0.f,0.f,0.f,0.f}, acc1 = {0.f,0.f,0.f,0.f};
    float m = -INFINITY, lsum = 0.f;
    const float scale = 0.17677669529663687f;   // 1/sqrt(32)
    const f32x4 zf = {0.f,0.f,0.f,0.f};

    const int sr = tid >> 2, sc = tid & 3;      // stage: 64 rows x 4 chunks

    for (int kt = 0; kt < 8; ++kt) {
        const int k0 = kt << 6;
        __syncthreads();                        // prev tile fully consumed
        {
            int t = k0 + sr;
            uint4 kvv = make_uint4(0,0,0,0), vvv = make_uint4(0,0,0,0);
            if (t < TT) {
                const ushort_t* bp = qkv + (size_t)(b*TT + t)*384 + hh*HD + sc*8;
                kvv = *reinterpret_cast<const uint4*>(bp + 128);
                vvv = *reinterpret_cast<const uint4*>(bp + 256);
            }
            *reinterpret_cast<uint4*>(&Ks[sr][sc*8]) = kvv;
            *reinterpret_cast<uint2*>(&Vs[sr][sc*8])     = make_uint2(vvv.x, vvv.y);
            *reinterpret_cast<uint2*>(&Vs[sr][sc*8 + 4]) = make_uint2(vvv.z, vvv.w);
        }
        __syncthreads();

        // V relayout into fragment-linear VB (concurrent with QK^T+softmax)
        {
            int kch = tid >> 7, dh = (tid >> 6) & 1, gg = (tid >> 4) & 3, nn = tid & 15;
            ushort_t tmp[8];
            #pragma unroll
            for (int j = 0; j < 8; ++j) tmp[j] = Vs[kch*32 + gg*8 + j][dh*16 + nn];
            *reinterpret_cast<uint4*>(&VB[kch][dh][gg][nn][0]) = *reinterpret_cast<uint4*>(tmp);
        }

        // S^T = K · Q^T : 4 tiles of 16 kcols
        f32x4 s[4];
        #pragma unroll
        for (int c = 0; c < 4; ++c) {
            short8 ak = *reinterpret_cast<const short8*>(&Ks[c*16 + n][g*8]);
            s[c] = __builtin_amdgcn_mfma_f32_16x16x32_bf16(ak, qf, zf, 0, 0, 0);
        }

        // bias + mask + online softmax (row = qrow = lane&15)
        float sv[16];
        float tmax = -INFINITY;
        #pragma unroll
        for (int c = 0; c < 4; ++c)
            #pragma unroll
            for (int r = 0; r < 4; ++r) {
                int kc = k0 + c*16 + g*4 + r;
                float bia = rl[kc - qrow + (MAXLEN_-1)];
                float v = (kc < TT) ? fmaf(s[c][r], scale, bia) : -1e30f;
                sv[c*4 + r] = v;
                tmax = fmaxf(tmax, v);
            }
        tmax = fmaxf(tmax, __shfl_xor(tmax, 16));
        tmax = fmaxf(tmax, __shfl_xor(tmax, 32));
        float mnew = fmaxf(m, tmax);
        float corr = __expf(m - mnew);
        m = mnew;
        float ps = 0.f;
        #pragma unroll
        for (int r = 0; r < 16; ++r) { float e = __expf(sv[r] - mnew); sv[r] = e; ps += e; }
        ps += __shfl_xor(ps, 16);
        ps += __shfl_xor(ps, 32);
        lsum = fmaf(lsum, corr, ps);

        // pack + exchange: chain A = kcols 0..31 (sv[0..7]), chain B = kcols 32..63 (sv[8..15])
        int src0 = n + ((g & 1) << 5);
        int src1 = src0 + 16;
        int t0 = (g < 2);
        union { unsigned wd[4]; short8 v; } PA, PB;
        {
            unsigned pk0lo = bf16r(sv[0]) | (bf16r(sv[1]) << 16);
            unsigned pk0hi = bf16r(sv[2]) | (bf16r(sv[3]) << 16);
            unsigned pk1lo = bf16r(sv[4]) | (bf16r(sv[5]) << 16);
            unsigned pk1hi = bf16r(sv[6]) | (bf16r(sv[7]) << 16);
            unsigned a0 = __shfl((int)pk0lo, src0), c0_ = __shfl((int)pk1lo, src0);
            unsigned a1 = __shfl((int)pk0hi, src0), c1_ = __shfl((int)pk1hi, src0);
            unsigned a2 = __shfl((int)pk0lo, src1), c2_ = __shfl((int)pk1lo, src1);
            unsigned a3 = __shfl((int)pk0hi, src1), c3_ = __shfl((int)pk1hi, src1);
            PA.wd[0] = t0 ? a0 : c0_; PA.wd[1] = t0 ? a1 : c1_;
            PA.wd[2] = t0 ? a2 : c2_; PA.wd[3] = t0 ? a3 : c3_;
        }
        {
            unsigned pk0lo = bf16r(sv[8])  | (bf16r(sv[9])  << 16);
            unsigned pk0hi = bf16r(sv[10]) | (bf16r(sv[11]) << 16);
            unsigned pk1lo = bf16r(sv[12]) | (bf16r(sv[13]) << 16);
            unsigned pk1hi = bf16r(sv[14]) | (bf16r(sv[15]) << 16);
            unsigned a0 = __shfl((int)pk0lo, src0), c0_ = __shfl((int)pk1lo, src0);
            unsigned a1 = __shfl((int)pk0hi, src0), c1_ = __shfl((int)pk1hi, src0);
            unsigned a2 = __shfl((int)pk0lo, src1), c2_ = __shfl((int)pk1lo, src1);
            unsigned a3 = __shfl((int)pk0hi, src1), c3_ = __shfl((int)pk1hi, src1);
            PB.wd[0] = t0 ? a0 : c0_; PB.wd[1] = t0 ? a1 : c1_;
            PB.wd[2] = t0 ? a2 : c2_; PB.wd[3] = t0 ? a3 : c3_;
        }

        __syncthreads();                        // VB ready
        short8 a00 = *reinterpret_cast<const short8*>(&VB[0][0][g][n][0]);
        short8 a01 = *reinterpret_cast<const short8*>(&VB[0][1][g][n][0]);
        short8 a10 = *reinterpret_cast<const short8*>(&VB[1][0][g][n][0]);
        short8 a11 = *reinterpret_cast<const short8*>(&VB[1][1][g][n][0]);
        #pragma unroll
        for (int r = 0; r < 4; ++r) { acc0[r] *= corr; acc1[r] *= corr; }
        acc0 = __builtin_amdgcn_mfma_f32_16x16x32_bf16(a00, PA.v, acc0, 0, 0, 0);
        acc0 = __builtin_amdgcn_mfma_f32_16x16x32_bf16(a10, PB.v, acc0, 0, 0, 0);
        acc1 = __builtin_amdgcn_mfma_f32_16x16x32_bf16(a01, PA.v, acc1, 0, 0, 0);
        acc1 = __builtin_amdgcn_mfma_f32_16x16x32_bf16(a11, PB.v, acc1, 0, 0, 0);
    }

    if (qv) {
        float inv = 1.f / lsum;
        #pragma unroll
        for (int r = 0; r < 4; ++r) {
            int d0 = g*4 + r;
            o[(size_t)(b*TT + qrow)*DIM + hh*HD + d0]      = (ushort_t)bf16r(acc0[r] * inv);
            o[(size_t)(b*TT + qrow)*DIM + hh*HD + 16 + d0] = (ushort_t)bf16r(acc1[r] * inv);
        }
    }
}

// ---------------- mean-pool + LN + classifier ----------------
__global__ __launch_bounds__(128) void final_kernel(
    const float* __restrict__ h, const float* __restrict__ g,
    const float* __restrict__ bt, const float* __restrict__ cls_w,
    const float* __restrict__ cls_b, float* __restrict__ out)
{
    int b = blockIdx.x, d = threadIdx.x;
    float s = 0.f;
    for (int t = 0; t < TT; ++t) s += h[((size_t)b*TT + t)*DIM + d];
    float pooled = s * (1.f / TT);
    __shared__ float sm[4];
    float v1 = pooled, v2 = pooled * pooled;
    #pragma unroll
    for (int off = 1; off < 64; off <<= 1) { v1 += __shfl_xor(v1, off); v2 += __shfl_xor(v2, off); }
    int wave = threadIdx.x >> 6, lane = threadIdx.x & 63;
    if (lane == 0) { sm[wave*2] = v1; sm[wave*2+1] = v2; }
    __syncthreads();
    float mean = (sm[0] + sm[2]) * (1.f/128.f);
    float var  = (sm[1] + sm[3]) * (1.f/128.f) - mean*mean;
    float xn = (pooled - mean) * rsqrtf(var + 1e-5f) * g[d] + bt[d];
    __shared__ float px[DIM];
    px[d] = xn;
    __syncthreads();
    if (d < NCLS_) {
        float a = cls_b[d];
        for (int i = 0; i < DIM; ++i) a = fmaf(px[i], cls_w[i*NCLS_ + d], a);
        out[b*NCLS_ + d] = a;
    }
}

// ---------------- host ----------------
extern "C" void kernel_launch(void* const* d_in, const int* in_sizes, int n_in,
                              void* d_out, int out_size, void* d_ws, size_t ws_size,
                              hipStream_t stream)
{
    (void)in_sizes; (void)n_in; (void)out_size; (void)ws_size;
    const float* x1      = (const float*)d_in[0];
    const float* proj_w  = (const float*)d_in[1];
    const float* proj_b  = (const float*)d_in[2];
    const float* queries = (const float*)d_in[3];
    const float* fc_w    = (const float*)d_in[4];
    const float* fc_b    = (const float*)d_in[5];
    const float* embed_w = (const float*)d_in[6];
    const float* embed_b = (const float*)d_in[7];
    const float* wqkv    = (const float*)d_in[8];
    const float* bqkv    = (const float*)d_in[9];
    const float* wo      = (const float*)d_in[10];
    const float* bo      = (const float*)d_in[11];
    const float* w1      = (const float*)d_in[12];
    const float* b1      = (const float*)d_in[13];
    const float* w2      = (const float*)d_in[14];
    const float* b2      = (const float*)d_in[15];
    const float* ln1_g   = (const float*)d_in[16];
    const float* ln1_b   = (const float*)d_in[17];
    const float* ln2_g   = (const float*)d_in[18];
    const float* ln2_b   = (const float*)d_in[19];
    const float* rel_t   = (const float*)d_in[20];
    const float* final_g = (const float*)d_in[21];
    const float* final_b = (const float*)d_in[22];
    const float* cls_w   = (const float*)d_in[23];
    const float* cls_b   = (const float*)d_in[24];

    float* ws     = (float*)d_ws;
    float* h      = ws;                               // MM*128 f32
    ushort_t* hb    = (ushort_t*)(h + (size_t)MM*DIM);     // MM*128 bf16
    ushort_t* qkvb  = hb    + (size_t)MM*DIM;         // MM*384 bf16
    ushort_t* attno = qkvb  + (size_t)MM*384;         // MM*128 bf16
    ushort_t* ffm   = attno + (size_t)MM*DIM;         // MM*512 bf16
    ushort_t* wts   = ffm   + (size_t)MM*FFD;         // 1179648 bf16
    float* alpha  = (float*)(wts + 1179648);          // 16
    float* Emat   = alpha + 16;                       // 10*128
    float* c0     = Emat + QOUT_*DIM;                 // 128

    enc_pre_kernel<<<1, 128, 0, stream>>>(proj_w, proj_b, queries, fc_w, fc_b,
                                          embed_w, embed_b, alpha, Emat, c0);
    wtrans_kernel<<<288, 256, 0, stream>>>(wqkv, wo, w1, w2, wts);
    enc_kernel<<<MM, 64, 0, stream>>>(x1, alpha, Emat, c0, h, hb);

    for (int l = 0; l < NL; ++l) {
        const ushort_t* wqkv_t = wts + (size_t)l*49152;
        const ushort_t* wo_t   = wts + 294912 + (size_t)l*16384;
        const ushort_t* w1_t   = wts + 393216 + (size_t)l*65536;
        const ushort_t* w2_t   = wts + 786432 + (size_t)l*65536;

        gemm_mfma_kernel<128><<<dim3(384/64, MM/128), 256, 0, stream>>>(
            hb, wqkv_t, bqkv + l*3*DIM, qkvb, 384, DIM, 0, 1);
        attn_mfma_kernel<<<BB*NHEADS*8, 256, 0, stream>>>(
            qkvb, rel_t + l*RELLEN, attno);
        gemm_ln_kernel<<<MM/32, 256, 0, stream>>>(
            attno, wo_t, bo + l*DIM, h, hb, ln1_g + l*DIM, ln1_b + l*DIM, DIM);
        gemm_mfma_kernel<128><<<dim3(FFD/64, MM/128), 256, 0, stream>>>(
            hb, w1_t, b1 + l*FFD, ffm, FFD, DIM, 1, 1);
        gemm_ln_kernel<<<MM/32, 256, 0, stream>>>(
            ffm, w2_t, b2 + l*DIM, h, hb, ln2_g + l*DIM, ln2_b + l*DIM, FFD);
    }

    final_kernel<<<BB, 128, 0, stream>>>(h, final_g, final_b, cls_w, cls_b, (float*)d_out);
}

// Round 5
// 411.502 us; speedup vs baseline: 4.9502x; 1.1163x over previous
//
#include <hip/hip_runtime.h>
#include <hip/hip_bf16.h>
#include <cmath>

#define NL      6
#define NHEADS  4
#define DIM     128
#define FFD     512
#define CMID_   8
#define COUT_   16
#define QOUT_   10
#define MAXLEN_ 512
#define NCLS_   3
#define BB      32
#define TT      500
#define FIN_    232
#define MM      (BB*TT)
#define HD      32
#define RELLEN  (2*MAXLEN_-1)

typedef __attribute__((ext_vector_type(8))) short short8;
typedef __attribute__((ext_vector_type(4))) float f32x4;
typedef unsigned short ushort_t;

__device__ inline unsigned bf16r(float x) {   // RNE float->bf16 bits (finite inputs)
    unsigned u = __float_as_uint(x);
    return (u + 0x7fffu + ((u >> 16) & 1u)) >> 16;
}

// ---------------- encoder precompute (1 block) ----------------
__global__ __launch_bounds__(128) void enc_pre_kernel(
    const float* __restrict__ proj_w, const float* __restrict__ proj_b,
    const float* __restrict__ queries, const float* __restrict__ fc_w,
    const float* __restrict__ fc_b, const float* __restrict__ embed_w,
    const float* __restrict__ embed_b,
    float* __restrict__ alpha, float* __restrict__ E, float* __restrict__ c0)
{
    __shared__ float pw[CMID_], cb[CMID_], gam[COUT_], del[COUT_];
    int t = threadIdx.x;
    if (t < CMID_) { pw[t] = proj_w[t]; cb[t] = proj_b[t] + ((t & 1) ? 1.f : 0.f); }
    __syncthreads();
    if (t < QOUT_) {
        float a = 0.f;
        for (int c = 0; c < CMID_; ++c) a += pw[c] * queries[t*CMID_ + c];
        alpha[t] = a;
    }
    if (t < COUT_) {
        float gg = 0.f, dd = 0.f;
        for (int c = 0; c < CMID_; ++c) {
            gg += pw[c] * fc_w[c*COUT_ + t];
            dd += cb[c] * fc_w[c*COUT_ + t];
        }
        gam[t] = gg; del[t] = dd + fc_b[t];
    }
    __syncthreads();
    for (int i = t; i < QOUT_*DIM; i += 128) {
        int q = i / DIM, d = i % DIM;
        float e = 0.f;
        for (int o = 0; o < COUT_; ++o) e += gam[o] * embed_w[(o*QOUT_ + q)*DIM + d];
        E[i] = e;
    }
    {
        float c = embed_b[t];
        for (int o = 0; o < COUT_; ++o) {
            float dl = del[o];
            for (int q = 0; q < QOUT_; ++q) c += dl * embed_w[(o*QOUT_ + q)*DIM + t];
        }
        c0[t] = c;
    }
}

// ---------------- encoder main ----------------
__global__ __launch_bounds__(64) void enc_kernel(
    const float* __restrict__ x1, const float* __restrict__ alpha,
    const float* __restrict__ E, const float* __restrict__ c0,
    float* __restrict__ h, ushort_t* __restrict__ hb)
{
    int bt = blockIdx.x;
    int lane = threadIdx.x;
    const float* xr = x1 + (size_t)bt * FIN_;
    float xv[4];
    bool vld[4];
    #pragma unroll
    for (int i = 0; i < 4; ++i) {
        int f = lane + (i << 6);
        vld[i] = (f < FIN_);
        xv[i] = vld[i] ? xr[f] : 0.f;
    }
    float vmax = -INFINITY, vmin = INFINITY;
    #pragma unroll
    for (int i = 0; i < 4; ++i) if (vld[i]) { vmax = fmaxf(vmax, xv[i]); vmin = fminf(vmin, xv[i]); }
    #pragma unroll
    for (int off = 1; off < 64; off <<= 1) {
        vmax = fmaxf(vmax, __shfl_xor(vmax, off));
        vmin = fminf(vmin, __shfl_xor(vmin, off));
    }
    float mq[QOUT_];
    for (int q = 0; q < QOUT_; ++q) {
        float a = alpha[q];
        float Mx = (a >= 0.f) ? a * vmax : a * vmin;
        float se = 0.f, sx = 0.f;
        #pragma unroll
        for (int i = 0; i < 4; ++i) if (vld[i]) {
            float e = __expf(fmaf(a, xv[i], -Mx));
            se += e; sx += e * xv[i];
        }
        #pragma unroll
        for (int off = 1; off < 64; off <<= 1) { se += __shfl_xor(se, off); sx += __shfl_xor(sx, off); }
        mq[q] = sx / se;
    }
    #pragma unroll
    for (int k = 0; k < 2; ++k) {
        int d = lane + (k << 6);
        float hv = c0[d];
        #pragma unroll
        for (int q = 0; q < QOUT_; ++q) hv = fmaf(mq[q], E[q*DIM + d], hv);
        h[(size_t)bt*DIM + d] = hv;
        hb[(size_t)bt*DIM + d] = (ushort_t)bf16r(hv);
    }
}

// ---------------- weight transpose + bf16 convert (once per launch) ----------------
__global__ __launch_bounds__(256) void wtrans_kernel(
    const float* __restrict__ wqkv, const float* __restrict__ wo,
    const float* __restrict__ w1, const float* __restrict__ w2,
    ushort_t* __restrict__ wts)
{
    int bid = blockIdx.x;
    const float* W; ushort_t* Wt; int K, N, tk, tn;
    if (bid < 72) {            // wqkv: K=128,N=384 -> 2x6 tiles x 6 layers
        int l = bid / 12, t = bid % 12; tk = t / 6; tn = t % 6; K = 128; N = 384;
        W = wqkv + (size_t)l*128*384; Wt = wts + (size_t)l*49152;
    } else if (bid < 96) {     // wo: 128x128 -> 2x2 x 6
        int q = bid - 72; int l = q / 4, t = q % 4; tk = t / 2; tn = t % 2; K = 128; N = 128;
        W = wo + (size_t)l*16384; Wt = wts + 294912 + (size_t)l*16384;
    } else if (bid < 192) {    // w1: K=128,N=512 -> 2x8 x 6
        int q = bid - 96; int l = q / 16, t = q % 16; tk = t / 8; tn = t % 8; K = 128; N = 512;
        W = w1 + (size_t)l*65536; Wt = wts + 393216 + (size_t)l*65536;
    } else {                   // w2: K=512,N=128 -> 8x2 x 6
        int q = bid - 192; int l = q / 16, t = q % 16; tk = t / 2; tn = t % 2; K = 512; N = 128;
        W = w2 + (size_t)l*65536; Wt = wts + 786432 + (size_t)l*65536;
    }
    int k0 = tk << 6, n0 = tn << 6;
    __shared__ float Ls[64][65];
    int tid = threadIdx.x;
    #pragma unroll
    for (int i = 0; i < 4; ++i) {
        int id = tid + 256*i;
        int r = id >> 4, ch = id & 15;
        float4 v = *reinterpret_cast<const float4*>(W + (size_t)(k0+r)*N + n0 + ch*4);
        Ls[ch*4+0][r] = v.x; Ls[ch*4+1][r] = v.y; Ls[ch*4+2][r] = v.z; Ls[ch*4+3][r] = v.w;
    }
    __syncthreads();
    #pragma unroll
    for (int i = 0; i < 4; ++i) {
        int id = tid + 256*i;
        int rr = id >> 4, ch = id & 15;
        uint2 o2;
        o2.x = bf16r(Ls[rr][ch*4+0]) | (bf16r(Ls[rr][ch*4+1]) << 16);
        o2.y = bf16r(Ls[rr][ch*4+2]) | (bf16r(Ls[rr][ch*4+3]) << 16);
        *reinterpret_cast<uint2*>(Wt + (size_t)(n0+rr)*K + k0 + ch*4) = o2;
    }
}

// ---------------- bf16 MFMA GEMM (qkv projection) ----------------
template<int BM>
__global__ __launch_bounds__(256) void gemm_mfma_kernel(
    const ushort_t* __restrict__ A, const ushort_t* __restrict__ Wt,
    const float* __restrict__ bias, void* __restrict__ C,
    int N, int K, int relu, int obf16)
{
    constexpr int MREP = BM / 32;
    constexpr int APT  = BM / 32;
    __shared__ __align__(16) ushort_t As[BM * 64];
    __shared__ __align__(16) ushort_t Bs[64 * 64];
    const int tid = threadIdx.x;
    const int row0 = blockIdx.y * BM, col0 = blockIdx.x << 6;
    const int w = tid >> 6, lane = tid & 63, g = lane >> 4, n = lane & 15;
    const int wr = w & 1, wc = w >> 1;
    f32x4 acc[MREP][2];
    #pragma unroll
    for (int mt = 0; mt < MREP; ++mt)
        #pragma unroll
        for (int nt = 0; nt < 2; ++nt) acc[mt][nt] = (f32x4){0.f,0.f,0.f,0.f};

    for (int k0 = 0; k0 < K; k0 += 64) {
        __syncthreads();
        #pragma unroll
        for (int i = 0; i < APT; ++i) {
            int id = tid + 256*i;
            int r = id >> 3, c = id & 7;
            uint4 v = *reinterpret_cast<const uint4*>(A + (size_t)(row0 + r)*K + k0 + c*8);
            *reinterpret_cast<uint4*>(As + r*64 + ((c ^ (r & 7)) << 3)) = v;
        }
        #pragma unroll
        for (int i = 0; i < 2; ++i) {
            int id = tid + 256*i;
            int r = id >> 3, c = id & 7;
            uint4 v = *reinterpret_cast<const uint4*>(Wt + (size_t)(col0 + r)*K + k0 + c*8);
            *reinterpret_cast<uint4*>(Bs + r*64 + ((c ^ (r & 7)) << 3)) = v;
        }
        __syncthreads();
        #pragma unroll
        for (int ks = 0; ks < 2; ++ks) {
            short8 af[MREP], bfr[2];
            #pragma unroll
            for (int mt = 0; mt < MREP; ++mt) {
                int r = wr*(BM/2) + mt*16 + n;
                af[mt] = *reinterpret_cast<const short8*>(As + r*64 + (((ks*4 + g) ^ (r & 7)) << 3));
            }
            #pragma unroll
            for (int nt = 0; nt < 2; ++nt) {
                int r = wc*32 + nt*16 + n;
                bfr[nt] = *reinterpret_cast<const short8*>(Bs + r*64 + (((ks*4 + g) ^ (r & 7)) << 3));
            }
            #pragma unroll
            for (int mt = 0; mt < MREP; ++mt)
                #pragma unroll
                for (int nt = 0; nt < 2; ++nt)
                    acc[mt][nt] = __builtin_amdgcn_mfma_f32_16x16x32_bf16(af[mt], bfr[nt], acc[mt][nt], 0, 0, 0);
        }
    }
    #pragma unroll
    for (int mt = 0; mt < MREP; ++mt) {
        #pragma unroll
        for (int nt = 0; nt < 2; ++nt) {
            int col = col0 + wc*32 + nt*16 + n;
            float bv = bias[col];
            #pragma unroll
            for (int r4 = 0; r4 < 4; ++r4) {
                int row = row0 + wr*(BM/2) + mt*16 + g*4 + r4;
                float v = acc[mt][nt][r4] + bv;
                if (relu) v = fmaxf(v, 0.f);
                if (obf16) ((ushort_t*)C)[(size_t)row*N + col] = (ushort_t)bf16r(v);
                else       ((float*)C)[(size_t)row*N + col] = v;
            }
        }
    }
}

// ---------------- fused GEMM + bias + residual + LayerNorm (wo path, K=128) -------
__global__ __launch_bounds__(256) void gemm_ln_kernel(
    const ushort_t* __restrict__ A, const ushort_t* __restrict__ Wt,
    const float* __restrict__ bias, float* __restrict__ h, ushort_t* __restrict__ hb,
    const float* __restrict__ lng, const float* __restrict__ lnb, int K)
{
    __shared__ __align__(16) ushort_t As[32 * 64];
    __shared__ __align__(16) ushort_t Bs[128 * 64];
    __shared__ float red[4][32][2];
    __shared__ float stats[32][2];
    const int tid = threadIdx.x;
    const int row0 = blockIdx.x << 5;
    const int wc = tid >> 6, lane = tid & 63, g = lane >> 4, n = lane & 15;
    f32x4 acc[2][2];
    #pragma unroll
    for (int mt = 0; mt < 2; ++mt)
        #pragma unroll
        for (int nt = 0; nt < 2; ++nt) acc[mt][nt] = (f32x4){0.f,0.f,0.f,0.f};

    for (int k0 = 0; k0 < K; k0 += 64) {
        __syncthreads();
        {
            int r = tid >> 3, c = tid & 7;
            uint4 v = *reinterpret_cast<const uint4*>(A + (size_t)(row0 + r)*K + k0 + c*8);
            *reinterpret_cast<uint4*>(As + r*64 + ((c ^ (r & 7)) << 3)) = v;
        }
        #pragma unroll
        for (int i = 0; i < 4; ++i) {
            int id = tid + 256*i;
            int r = id >> 3, c = id & 7;
            uint4 v = *reinterpret_cast<const uint4*>(Wt + (size_t)r*K + k0 + c*8);
            *reinterpret_cast<uint4*>(Bs + r*64 + ((c ^ (r & 7)) << 3)) = v;
        }
        __syncthreads();
        #pragma unroll
        for (int ks = 0; ks < 2; ++ks) {
            short8 af[2], bfr[2];
            #pragma unroll
            for (int mt = 0; mt < 2; ++mt) {
                int r = mt*16 + n;
                af[mt] = *reinterpret_cast<const short8*>(As + r*64 + (((ks*4 + g) ^ (r & 7)) << 3));
            }
            #pragma unroll
            for (int nt = 0; nt < 2; ++nt) {
                int r = wc*32 + nt*16 + n;
                bfr[nt] = *reinterpret_cast<const short8*>(Bs + r*64 + (((ks*4 + g) ^ (r & 7)) << 3));
            }
            #pragma unroll
            for (int mt = 0; mt < 2; ++mt)
                #pragma unroll
                for (int nt = 0; nt < 2; ++nt)
                    acc[mt][nt] = __builtin_amdgcn_mfma_f32_16x16x32_bf16(af[mt], bfr[nt], acc[mt][nt], 0, 0, 0);
        }
    }

    float vals[2][2][4];
    #pragma unroll
    for (int nt = 0; nt < 2; ++nt) {
        int col = wc*32 + nt*16 + n;
        float bv = bias[col];
        #pragma unroll
        for (int mt = 0; mt < 2; ++mt)
            #pragma unroll
            for (int r4 = 0; r4 < 4; ++r4) {
                int row = row0 + mt*16 + g*4 + r4;
                vals[mt][nt][r4] = acc[mt][nt][r4] + bv + h[(size_t)row*DIM + col];
            }
    }
    #pragma unroll
    for (int mt = 0; mt < 2; ++mt)
        #pragma unroll
        for (int r4 = 0; r4 < 4; ++r4) {
            float s  = vals[mt][0][r4] + vals[mt][1][r4];
            float s2 = vals[mt][0][r4]*vals[mt][0][r4] + vals[mt][1][r4]*vals[mt][1][r4];
            #pragma unroll
            for (int off = 1; off < 16; off <<= 1) {
                s  += __shfl_xor(s, off);
                s2 += __shfl_xor(s2, off);
            }
            if (n == 0) { red[wc][mt*16 + g*4 + r4][0] = s; red[wc][mt*16 + g*4 + r4][1] = s2; }
        }
    __syncthreads();
    if (tid < 32) {
        float s = 0.f, s2 = 0.f;
        #pragma unroll
        for (int ww = 0; ww < 4; ++ww) { s += red[ww][tid][0]; s2 += red[ww][tid][1]; }
        float mean = s * (1.f/128.f);
        float var  = s2 * (1.f/128.f) - mean*mean;
        stats[tid][0] = mean;
        stats[tid][1] = rsqrtf(var + 1e-5f);
    }
    __syncthreads();
    #pragma unroll
    for (int nt = 0; nt < 2; ++nt) {
        int col = wc*32 + nt*16 + n;
        float gv = lng[col], bv = lnb[col];
        #pragma unroll
        for (int mt = 0; mt < 2; ++mt)
            #pragma unroll
            for (int r4 = 0; r4 < 4; ++r4) {
                int rloc = mt*16 + g*4 + r4;
                int row = row0 + rloc;
                float y = (vals[mt][nt][r4] - stats[rloc][0]) * stats[rloc][1] * gv + bv;
                h[(size_t)row*DIM + col]  = y;
                hb[(size_t)row*DIM + col] = (ushort_t)bf16r(y);
            }
    }
}

// ---------------- fully fused FFN: h = LN2(h + relu(hb@W1+b1)@W2 + b2) ----------------
// 32 rows per block. Phase 1: Mid(LDS) = relu(hb@W1+b1) via D=W1t(A)xhb(B) -> lane holds
// 4 consecutive k1 -> b64 LDS writes. Phase 2: out = Mid@W2 via D=W2t(A)xMid(B) -> lane
// holds 4 consecutive out-cols -> float4 epilogue with residual+LN.
__global__ __launch_bounds__(256) void ffn_kernel(
    const ushort_t* __restrict__ hbin, const ushort_t* __restrict__ W1t,
    const ushort_t* __restrict__ W2t, const float* __restrict__ b1v,
    const float* __restrict__ b2v, float* __restrict__ h, ushort_t* __restrict__ hb,
    const float* __restrict__ lng, const float* __restrict__ lnb)
{
    __shared__ __align__(16) ushort_t As[32 * 128];     // hb tile  (8 KB)
    __shared__ __align__(16) ushort_t Wbuf[128 * 128];  // weight chunk (32 KB)
    __shared__ __align__(16) ushort_t Mid[32 * 512];    // mid tile (32 KB)
    __shared__ float red[4][32][2];
    __shared__ float stats[32][2];
    const int tid = threadIdx.x;
    const int row0 = blockIdx.x << 5;
    const int w = tid >> 6, lane = tid & 63, g = lane >> 4, n = lane & 15;

    // stage A-tile (32 x 128)
    #pragma unroll
    for (int i = 0; i < 2; ++i) {
        int id = tid + 256*i;
        int r = id >> 4, c = id & 15;
        uint4 v = *reinterpret_cast<const uint4*>(hbin + (size_t)(row0 + r)*DIM + c*8);
        *reinterpret_cast<uint4*>(As + r*128 + ((c ^ (r & 7)) << 3)) = v;
    }

    // ---- phase 1: Mid = relu(A @ W1 + b1), 4 chunks of 128 cols ----
    for (int cc = 0; cc < 4; ++cc) {
        __syncthreads();                       // prev compute done / As staged
        #pragma unroll
        for (int i = 0; i < 8; ++i) {          // stage W1t chunk [128 k1][128 k]
            int id = tid + 256*i;
            int r = id >> 4, c = id & 15;
            uint4 v = *reinterpret_cast<const uint4*>(W1t + (size_t)(cc*128 + r)*DIM + c*8);
            *reinterpret_cast<uint4*>(Wbuf + r*128 + ((c ^ (r & 7)) << 3)) = v;
        }
        __syncthreads();
        f32x4 acc[2][2];                       // [at][mt]
        #pragma unroll
        for (int a = 0; a < 2; ++a)
            #pragma unroll
            for (int b = 0; b < 2; ++b) acc[a][b] = (f32x4){0.f,0.f,0.f,0.f};
        #pragma unroll
        for (int ks = 0; ks < 4; ++ks) {
            short8 aw[2], bh[2];
            #pragma unroll
            for (int at = 0; at < 2; ++at) {
                int r = w*32 + at*16 + n;
                aw[at] = *reinterpret_cast<const short8*>(Wbuf + r*128 + (((ks*4 + g) ^ (r & 7)) << 3));
            }
            #pragma unroll
            for (int mt = 0; mt < 2; ++mt) {
                int r = mt*16 + n;
                bh[mt] = *reinterpret_cast<const short8*>(As + r*128 + (((ks*4 + g) ^ (r & 7)) << 3));
            }
            #pragma unroll
            for (int at = 0; at < 2; ++at)
                #pragma unroll
                for (int mt = 0; mt < 2; ++mt)
                    acc[at][mt] = __builtin_amdgcn_mfma_f32_16x16x32_bf16(aw[at], bh[mt], acc[at][mt], 0, 0, 0);
        }
        #pragma unroll
        for (int at = 0; at < 2; ++at) {
            int k1b = cc*128 + w*32 + at*16 + g*4;     // 4 consecutive k1 per lane
            float4 bb = *reinterpret_cast<const float4*>(b1v + k1b);
            int ch = k1b >> 3;                         // 16B-chunk index in Mid row
            int halfoff = (g & 1) * 4;                 // 8B half within chunk
            #pragma unroll
            for (int mt = 0; mt < 2; ++mt) {
                int mrow = mt*16 + n;
                float v0 = fmaxf(acc[at][mt][0] + bb.x, 0.f);
                float v1 = fmaxf(acc[at][mt][1] + bb.y, 0.f);
                float v2 = fmaxf(acc[at][mt][2] + bb.z, 0.f);
                float v3 = fmaxf(acc[at][mt][3] + bb.w, 0.f);
                uint2 pk;
                pk.x = bf16r(v0) | (bf16r(v1) << 16);
                pk.y = bf16r(v2) | (bf16r(v3) << 16);
                *reinterpret_cast<uint2*>(Mid + mrow*512 + ((ch ^ (mrow & 7)) << 3) + halfoff) = pk;
            }
        }
    }

    // ---- phase 2: out = Mid @ W2, fused bias + residual + LN ----
    f32x4 oacc[2][2];                          // [ct][mt]
    #pragma unroll
    for (int a = 0; a < 2; ++a)
        #pragma unroll
        for (int b = 0; b < 2; ++b) oacc[a][b] = (f32x4){0.f,0.f,0.f,0.f};
    for (int kc = 0; kc < 4; ++kc) {
        __syncthreads();                       // Mid complete / prev chunk consumed
        #pragma unroll
        for (int i = 0; i < 8; ++i) {          // stage W2t chunk [128 c][128 k]
            int id = tid + 256*i;
            int r = id >> 4, c = id & 15;
            uint4 v = *reinterpret_cast<const uint4*>(W2t + (size_t)r*FFD + kc*128 + c*8);
            *reinterpret_cast<uint4*>(Wbuf + r*128 + ((c ^ (r & 7)) << 3)) = v;
        }
        __syncthreads();
        #pragma unroll
        for (int ks = 0; ks < 4; ++ks) {
            short8 aw[2], bm[2];
            #pragma unroll
            for (int ct = 0; ct < 2; ++ct) {
                int r = w*32 + ct*16 + n;
                aw[ct] = *reinterpret_cast<const short8*>(Wbuf + r*128 + (((ks*4 + g) ^ (r & 7)) << 3));
            }
            #pragma unroll
            for (int mt = 0; mt < 2; ++mt) {
                int r = mt*16 + n;
                int ch = kc*16 + ks*4 + g;
                bm[mt] = *reinterpret_cast<const short8*>(Mid + r*512 + ((ch ^ (r & 7)) << 3));
            }
            #pragma unroll
            for (int ct = 0; ct < 2; ++ct)
                #pragma unroll
                for (int mt = 0; mt < 2; ++mt)
                    oacc[ct][mt] = __builtin_amdgcn_mfma_f32_16x16x32_bf16(aw[ct], bm[mt], oacc[ct][mt], 0, 0, 0);
        }
    }

    // epilogue: lane holds rows mt*16+n, cols w*32+ct*16+g*4 .. +3
    float vals[2][2][4];
    #pragma unroll
    for (int ct = 0; ct < 2; ++ct) {
        int colb = w*32 + ct*16 + g*4;
        float4 bb = *reinterpret_cast<const float4*>(b2v + colb);
        #pragma unroll
        for (int mt = 0; mt < 2; ++mt) {
            int mrow = row0 + mt*16 + n;
            float4 hres = *reinterpret_cast<const float4*>(h + (size_t)mrow*DIM + colb);
            vals[ct][mt][0] = oacc[ct][mt][0] + bb.x + hres.x;
            vals[ct][mt][1] = oacc[ct][mt][1] + bb.y + hres.y;
            vals[ct][mt][2] = oacc[ct][mt][2] + bb.z + hres.z;
            vals[ct][mt][3] = oacc[ct][mt][3] + bb.w + hres.w;
        }
    }
    #pragma unroll
    for (int mt = 0; mt < 2; ++mt) {
        float s = 0.f, s2 = 0.f;
        #pragma unroll
        for (int ct = 0; ct < 2; ++ct)
            #pragma unroll
            for (int r4 = 0; r4 < 4; ++r4) { float v = vals[ct][mt][r4]; s += v; s2 += v*v; }
        s  += __shfl_xor(s, 16);  s  += __shfl_xor(s, 32);
        s2 += __shfl_xor(s2, 16); s2 += __shfl_xor(s2, 32);
        if (g == 0) { red[w][mt*16 + n][0] = s; red[w][mt*16 + n][1] = s2; }
    }
    __syncthreads();
    if (tid < 32) {
        float s = 0.f, s2 = 0.f;
        #pragma unroll
        for (int ww = 0; ww < 4; ++ww) { s += red[ww][tid][0]; s2 += red[ww][tid][1]; }
        float mean = s * (1.f/128.f);
        float var  = s2 * (1.f/128.f) - mean*mean;
        stats[tid][0] = mean;
        stats[tid][1] = rsqrtf(var + 1e-5f);
    }
    __syncthreads();
    #pragma unroll
    for (int ct = 0; ct < 2; ++ct) {
        int colb = w*32 + ct*16 + g*4;
        float4 gv = *reinterpret_cast<const float4*>(lng + colb);
        float4 bv = *reinterpret_cast<const float4*>(lnb + colb);
        #pragma unroll
        for (int mt = 0; mt < 2; ++mt) {
            int rloc = mt*16 + n;
            int mrow = row0 + rloc;
            float mean = stats[rloc][0], rstd = stats[rloc][1];
            float y0 = (vals[ct][mt][0] - mean) * rstd * gv.x + bv.x;
            float y1 = (vals[ct][mt][1] - mean) * rstd * gv.y + bv.y;
            float y2 = (vals[ct][mt][2] - mean) * rstd * gv.z + bv.z;
            float y3 = (vals[ct][mt][3] - mean) * rstd * gv.w + bv.w;
            float4 yo = {y0, y1, y2, y3};
            *reinterpret_cast<float4*>(h + (size_t)mrow*DIM + colb) = yo;
            uint2 pk;
            pk.x = bf16r(y0) | (bf16r(y1) << 16);
            pk.y = bf16r(y2) | (bf16r(y3) << 16);
            *reinterpret_cast<uint2*>(hb + (size_t)mrow*DIM + colb) = pk;
        }
    }
}

// ---------------- MFMA bf16 flash attention (KVBLK=64) ----------------
__global__ __launch_bounds__(256) void attn_mfma_kernel(
    const ushort_t* __restrict__ qkv, const float* __restrict__ rel,
    ushort_t* __restrict__ o)
{
    __shared__ __align__(16) ushort_t Ks[64][40];          // [kcol][dim] 80B rows
    __shared__ __align__(16) ushort_t Vs[64][36];          // [kcol][dim] 72B rows
    __shared__ __align__(16) ushort_t VB[2][2][4][16][8];  // [kchalf][dimhalf][g][n][j]
    __shared__ float rl[RELLEN];
    const int bid = blockIdx.x;
    const int qt = bid & 7;
    const int bh = bid >> 3;
    const int hh = bh & 3, b = bh >> 2;
    const int tid  = threadIdx.x;
    const int wq   = tid >> 6;
    const int lane = tid & 63;
    const int g = lane >> 4, n = lane & 15;
    for (int i = tid; i < RELLEN; i += 256) rl[i] = rel[i];

    const int qrow = (qt << 6) + (wq << 4) + n;
    const bool qv = (qrow < TT);
    short8 qf = {0,0,0,0,0,0,0,0};
    if (qv) qf = *reinterpret_cast<const short8*>(qkv + (size_t)(b*TT + qrow)*384 + hh*HD + g*8);

    f32x4 acc0 = {0.f,0.f,0.f,0.f}, acc1 = {0.f,0.f,0.f,0.f};
    float m = -INFINITY, lsum = 0.f;
    const float scale = 0.17677669529663687f;   // 1/sqrt(32)
    const f32x4 zf = {0.f,0.f,0.f,0.f};

    const int sr = tid >> 2, sc = tid & 3;      // stage: 64 rows x 4 chunks

    for (int kt = 0; kt < 8; ++kt) {
        const int k0 = kt << 6;
        __syncthreads();                        // prev tile fully consumed
        {
            int t = k0 + sr;
            uint4 kvv = make_uint4(0,0,0,0), vvv = make_uint4(0,0,0,0);
            if (t < TT) {
                const ushort_t* bp = qkv + (size_t)(b*TT + t)*384 + hh*HD + sc*8;
                kvv = *reinterpret_cast<const uint4*>(bp + 128);
                vvv = *reinterpret_cast<const uint4*>(bp + 256);
            }
            *reinterpret_cast<uint4*>(&Ks[sr][sc*8]) = kvv;
            *reinterpret_cast<uint2*>(&Vs[sr][sc*8])     = make_uint2(vvv.x, vvv.y);
            *reinterpret_cast<uint2*>(&Vs[sr][sc*8 + 4]) = make_uint2(vvv.z, vvv.w);
        }
        __syncthreads();

        // V relayout into fragment-linear VB (concurrent with QK^T+softmax)
        {
            int kch = tid >> 7, dh = (tid >> 6) & 1, gg = (tid >> 4) & 3, nn = tid & 15;
            ushort_t tmp[8];
            #pragma unroll
            for (int j = 0; j < 8; ++j) tmp[j] = Vs[kch*32 + gg*8 + j][dh*16 + nn];
            *reinterpret_cast<uint4*>(&VB[kch][dh][gg][nn][0]) = *reinterpret_cast<uint4*>(tmp);
        }

        // S^T = K . Q^T : 4 tiles of 16 kcols
        f32x4 s[4];
        #pragma unroll
        for (int c = 0; c < 4; ++c) {
            short8 ak = *reinterpret_cast<const short8*>(&Ks[c*16 + n][g*8]);
            s[c] = __builtin_amdgcn_mfma_f32_16x16x32_bf16(ak, qf, zf, 0, 0, 0);
        }

        float sv[16];
        float tmax = -INFINITY;
        #pragma unroll
        for (int c = 0; c < 4; ++c)
            #pragma unroll
            for (int r = 0; r < 4; ++r) {
                int kc = k0 + c*16 + g*4 + r;
                float bia = rl[kc - qrow + (MAXLEN_-1)];
                float v = (kc < TT) ? fmaf(s[c][r], scale, bia) : -1e30f;
                sv[c*4 + r] = v;
                tmax = fmaxf(tmax, v);
            }
        tmax = fmaxf(tmax, __shfl_xor(tmax, 16));
        tmax = fmaxf(tmax, __shfl_xor(tmax, 32));
        float mnew = fmaxf(m, tmax);
        float corr = __expf(m - mnew);
        m = mnew;
        float ps = 0.f;
        #pragma unroll
        for (int r = 0; r < 16; ++r) { float e = __expf(sv[r] - mnew); sv[r] = e; ps += e; }
        ps += __shfl_xor(ps, 16);
        ps += __shfl_xor(ps, 32);
        lsum = fmaf(lsum, corr, ps);

        int src0 = n + ((g & 1) << 5);
        int src1 = src0 + 16;
        int t0 = (g < 2);
        union { unsigned wd[4]; short8 v; } PA, PB;
        {
            unsigned pk0lo = bf16r(sv[0]) | (bf16r(sv[1]) << 16);
            unsigned pk0hi = bf16r(sv[2]) | (bf16r(sv[3]) << 16);
            unsigned pk1lo = bf16r(sv[4]) | (bf16r(sv[5]) << 16);
            unsigned pk1hi = bf16r(sv[6]) | (bf16r(sv[7]) << 16);
            unsigned a0 = __shfl((int)pk0lo, src0), c0_ = __shfl((int)pk1lo, src0);
            unsigned a1 = __shfl((int)pk0hi, src0), c1_ = __shfl((int)pk1hi, src0);
            unsigned a2 = __shfl((int)pk0lo, src1), c2_ = __shfl((int)pk1lo, src1);
            unsigned a3 = __shfl((int)pk0hi, src1), c3_ = __shfl((int)pk1hi, src1);
            PA.wd[0] = t0 ? a0 : c0_; PA.wd[1] = t0 ? a1 : c1_;
            PA.wd[2] = t0 ? a2 : c2_; PA.wd[3] = t0 ? a3 : c3_;
        }
        {
            unsigned pk0lo = bf16r(sv[8])  | (bf16r(sv[9])  << 16);
            unsigned pk0hi = bf16r(sv[10]) | (bf16r(sv[11]) << 16);
            unsigned pk1lo = bf16r(sv[12]) | (bf16r(sv[13]) << 16);
            unsigned pk1hi = bf16r(sv[14]) | (bf16r(sv[15]) << 16);
            unsigned a0 = __shfl((int)pk0lo, src0), c0_ = __shfl((int)pk1lo, src0);
            unsigned a1 = __shfl((int)pk0hi, src0), c1_ = __shfl((int)pk1hi, src0);
            unsigned a2 = __shfl((int)pk0lo, src1), c2_ = __shfl((int)pk1lo, src1);
            unsigned a3 = __shfl((int)pk0hi, src1), c3_ = __shfl((int)pk1hi, src1);
            PB.wd[0] = t0 ? a0 : c0_; PB.wd[1] = t0 ? a1 : c1_;
            PB.wd[2] = t0 ? a2 : c2_; PB.wd[3] = t0 ? a3 : c3_;
        }

        __syncthreads();                        // VB ready
        short8 a00 = *reinterpret_cast<const short8*>(&VB[0][0][g][n][0]);
        short8 a01 = *reinterpret_cast<const short8*>(&VB[0][1][g][n][0]);
        short8 a10 = *reinterpret_cast<const short8*>(&VB[1][0][g][n][0]);
        short8 a11 = *reinterpret_cast<const short8*>(&VB[1][1][g][n][0]);
        #pragma unroll
        for (int r = 0; r < 4; ++r) { acc0[r] *= corr; acc1[r] *= corr; }
        acc0 = __builtin_amdgcn_mfma_f32_16x16x32_bf16(a00, PA.v, acc0, 0, 0, 0);
        acc0 = __builtin_amdgcn_mfma_f32_16x16x32_bf16(a10, PB.v, acc0, 0, 0, 0);
        acc1 = __builtin_amdgcn_mfma_f32_16x16x32_bf16(a01, PA.v, acc1, 0, 0, 0);
        acc1 = __builtin_amdgcn_mfma_f32_16x16x32_bf16(a11, PB.v, acc1, 0, 0, 0);
    }

    if (qv) {
        float inv = 1.f / lsum;
        #pragma unroll
        for (int r = 0; r < 4; ++r) {
            int d0 = g*4 + r;
            o[(size_t)(b*TT + qrow)*DIM + hh*HD + d0]      = (ushort_t)bf16r(acc0[r] * inv);
            o[(size_t)(b*TT + qrow)*DIM + hh*HD + 16 + d0] = (ushort_t)bf16r(acc1[r] * inv);
        }
    }
}

// ---------------- mean-pool + LN + classifier ----------------
__global__ __launch_bounds__(128) void final_kernel(
    const float* __restrict__ h, const float* __restrict__ g,
    const float* __restrict__ bt, const float* __restrict__ cls_w,
    const float* __restrict__ cls_b, float* __restrict__ out)
{
    int b = blockIdx.x, d = threadIdx.x;
    float s = 0.f;
    for (int t = 0; t < TT; ++t) s += h[((size_t)b*TT + t)*DIM + d];
    float pooled = s * (1.f / TT);
    __shared__ float sm[4];
    float v1 = pooled, v2 = pooled * pooled;
    #pragma unroll
    for (int off = 1; off < 64; off <<= 1) { v1 += __shfl_xor(v1, off); v2 += __shfl_xor(v2, off); }
    int wave = threadIdx.x >> 6, lane = threadIdx.x & 63;
    if (lane == 0) { sm[wave*2] = v1; sm[wave*2+1] = v2; }
    __syncthreads();
    float mean = (sm[0] + sm[2]) * (1.f/128.f);
    float var  = (sm[1] + sm[3]) * (1.f/128.f) - mean*mean;
    float xn = (pooled - mean) * rsqrtf(var + 1e-5f) * g[d] + bt[d];
    __shared__ float px[DIM];
    px[d] = xn;
    __syncthreads();
    if (d < NCLS_) {
        float a = cls_b[d];
        for (int i = 0; i < DIM; ++i) a = fmaf(px[i], cls_w[i*NCLS_ + d], a);
        out[b*NCLS_ + d] = a;
    }
}

// ---------------- host ----------------
extern "C" void kernel_launch(void* const* d_in, const int* in_sizes, int n_in,
                              void* d_out, int out_size, void* d_ws, size_t ws_size,
                              hipStream_t stream)
{
    (void)in_sizes; (void)n_in; (void)out_size; (void)ws_size;
    const float* x1      = (const float*)d_in[0];
    const float* proj_w  = (const float*)d_in[1];
    const float* proj_b  = (const float*)d_in[2];
    const float* queries = (const float*)d_in[3];
    const float* fc_w    = (const float*)d_in[4];
    const float* fc_b    = (const float*)d_in[5];
    const float* embed_w = (const float*)d_in[6];
    const float* embed_b = (const float*)d_in[7];
    const float* wqkv    = (const float*)d_in[8];
    const float* bqkv    = (const float*)d_in[9];
    const float* wo      = (const float*)d_in[10];
    const float* bo      = (const float*)d_in[11];
    const float* w1      = (const float*)d_in[12];
    const float* b1      = (const float*)d_in[13];
    const float* w2      = (const float*)d_in[14];
    const float* b2      = (const float*)d_in[15];
    const float* ln1_g   = (const float*)d_in[16];
    const float* ln1_b   = (const float*)d_in[17];
    const float* ln2_g   = (const float*)d_in[18];
    const float* ln2_b   = (const float*)d_in[19];
    const float* rel_t   = (const float*)d_in[20];
    const float* final_g = (const float*)d_in[21];
    const float* final_b = (const float*)d_in[22];
    const float* cls_w   = (const float*)d_in[23];
    const float* cls_b   = (const float*)d_in[24];

    float* ws     = (float*)d_ws;
    float* h      = ws;                                    // MM*128 f32
    ushort_t* hb    = (ushort_t*)(h + (size_t)MM*DIM);     // MM*128 bf16
    ushort_t* qkvb  = hb    + (size_t)MM*DIM;              // MM*384 bf16
    ushort_t* attno = qkvb  + (size_t)MM*384;              // MM*128 bf16
    ushort_t* wts   = attno + (size_t)MM*DIM;              // 1179648 bf16
    float* alpha  = (float*)(wts + 1179648);               // 16
    float* Emat   = alpha + 16;                            // 10*128
    float* c0     = Emat + QOUT_*DIM;                      // 128

    enc_pre_kernel<<<1, 128, 0, stream>>>(proj_w, proj_b, queries, fc_w, fc_b,
                                          embed_w, embed_b, alpha, Emat, c0);
    wtrans_kernel<<<288, 256, 0, stream>>>(wqkv, wo, w1, w2, wts);
    enc_kernel<<<MM, 64, 0, stream>>>(x1, alpha, Emat, c0, h, hb);

    for (int l = 0; l < NL; ++l) {
        const ushort_t* wqkv_t = wts + (size_t)l*49152;
        const ushort_t* wo_t   = wts + 294912 + (size_t)l*16384;
        const ushort_t* w1_t   = wts + 393216 + (size_t)l*65536;
        const ushort_t* w2_t   = wts + 786432 + (size_t)l*65536;

        gemm_mfma_kernel<128><<<dim3(384/64, MM/128), 256, 0, stream>>>(
            hb, wqkv_t, bqkv + l*3*DIM, qkvb, 384, DIM, 0, 1);
        attn_mfma_kernel<<<BB*NHEADS*8, 256, 0, stream>>>(
            qkvb, rel_t + l*RELLEN, attno);
        gemm_ln_kernel<<<MM/32, 256, 0, stream>>>(
            attno, wo_t, bo + l*DIM, h, hb, ln1_g + l*DIM, ln1_b + l*DIM, DIM);
        ffn_kernel<<<MM/32, 256, 0, stream>>>(
            hb, w1_t, w2_t, b1 + l*FFD, b2 + l*DIM, h, hb,
            ln2_g + l*DIM, ln2_b + l*DIM);
    }

    final_kernel<<<BB, 128, 0, stream>>>(h, final_g, final_b, cls_w, cls_b, (float*)d_out);
}